// Round 2
// baseline (483.449 us; speedup 1.0000x reference)
//
#include <hip/hip_runtime.h>
#include <cstdint>
#include <cstddef>

#define N_NODES 50000
#define N_EDGES 800000
#define F_IN    512
#define H_DIM   128
#define C_OUT   40
#define TOT_E   (N_EDGES + N_NODES)
#define KTOT    640             // P rows: h | u1 | u2 | u3 | u4
#define ZW      240             // Z row width: 5 blocks x 48
#define NZP     256             // Wzt rows padded to 256

typedef __attribute__((ext_vector_type(8))) __bf16 bf16x8;
typedef __attribute__((ext_vector_type(4))) float f32x4;

__device__ __forceinline__ unsigned short bf16_rne(float f) {
  unsigned int u = __float_as_uint(f);
  u += 0x7fffu + ((u >> 16) & 1u);
  return (unsigned short)(u >> 16);
}
__device__ __forceinline__ float bf16_lo_f(unsigned int u) { return __uint_as_float(u << 16); }
__device__ __forceinline__ float bf16_hi_f(unsigned int u) { return __uint_as_float(u & 0xffff0000u); }

// async global->LDS, 16B per lane; dest must be linear (base + lane*16)
#define GLOAD_LDS16(gp, lp)                                                        \
  __builtin_amdgcn_global_load_lds(                                                \
      (const __attribute__((address_space(1))) void*)(gp),                         \
      (__attribute__((address_space(3))) void*)(lp), 16, 0, 0)

// ----------------------------- setup kernels -------------------------------
// Single u64 atomic per edge: bits [40..63] = count, [0..39] = 2^-24 fixed-pt
// weighted degree. Returned old count = slot of edge in its dst bucket.

__global__ void edge_pass1_k(const int* __restrict__ dst, const float* __restrict__ ew,
                             unsigned long long* __restrict__ acc,
                             int* __restrict__ pos, int e) {
  int i = blockIdx.x * blockDim.x + threadIdx.x;
  if (i < e) {
    int d = dst[i];
    unsigned long long v = (1ull << 40) |
        (unsigned long long)(ew[i] * 16777216.0f + 0.5f);
    unsigned long long old = atomicAdd(&acc[d], v);
    pos[i] = (int)(old >> 40);
  }
}

__global__ void node_pass_k(const unsigned long long* __restrict__ acc,
                            float* __restrict__ dinv, int* __restrict__ cnt, int n) {
  int i = blockIdx.x * blockDim.x + threadIdx.x;
  if (i < n) {
    unsigned long long a = acc[i];
    double dfix = (double)(a & 0xFFFFFFFFFFull);
    float deg = (float)(dfix * (1.0 / 16777216.0) + 1.0);   // +1 self-loop
    dinv[i] = rsqrtf(deg);
    cnt[i] = (int)(a >> 40) + 1;                            // +1 self-loop
  }
}

__global__ __launch_bounds__(256) void block_reduce_k(const int* __restrict__ cnt,
                                                      int* bsum, int n) {
  __shared__ int s[256];
  int t = threadIdx.x;
  int i = blockIdx.x * 256 + t;
  s[t] = (i < n) ? cnt[i] : 0;
  __syncthreads();
  for (int off = 128; off; off >>= 1) {
    if (t < off) s[t] += s[t + off];
    __syncthreads();
  }
  if (t == 0) bsum[blockIdx.x] = s[0];
}

__global__ __launch_bounds__(256) void scan_bsums_k(int* bsum, int nb) {
  __shared__ int s[256];
  int t = threadIdx.x;
  s[t] = (t < nb) ? bsum[t] : 0;
  __syncthreads();
  for (int off = 1; off < 256; off <<= 1) {
    int v = (t >= off) ? s[t - off] : 0;
    __syncthreads();
    s[t] += v;
    __syncthreads();
  }
  if (t < nb) bsum[t] = (t == 0) ? 0 : s[t - 1];
}

__global__ __launch_bounds__(256) void scan_write_k(const int* __restrict__ cnt,
                                                    const int* __restrict__ bsum,
                                                    int* row_ptr, int n) {
  __shared__ int s[256];
  int t = threadIdx.x;
  int i = blockIdx.x * 256 + t;
  int c = (i < n) ? cnt[i] : 0;
  s[t] = c;
  __syncthreads();
  for (int off = 1; off < 256; off <<= 1) {
    int v = (t >= off) ? s[t - off] : 0;
    __syncthreads();
    s[t] += v;
    __syncthreads();
  }
  int ex = bsum[blockIdx.x] + ((t == 0) ? 0 : s[t - 1]);
  if (i < n) row_ptr[i] = ex;
  if (i == n - 1) row_ptr[n] = ex + c;
}

__global__ void scatter2_k(const int* __restrict__ src, const int* __restrict__ dst,
                           const float* __restrict__ ew, const int* __restrict__ pos,
                           const float* __restrict__ dinv, const int* __restrict__ rowp,
                           int2* __restrict__ csr, int e, int n) {
  int i = blockIdx.x * blockDim.x + threadIdx.x;
  if (i < e) {
    int s = src[i], d = dst[i];
    float w = dinv[s] * ew[i] * dinv[d];
    csr[rowp[d] + pos[i]] = make_int2(s, __float_as_int(w));
  } else if (i < e + n) {
    int v = i - e;
    float di = dinv[v];
    csr[rowp[v + 1] - 1] = make_int2(v, __float_as_int(di * di));  // self-loop last
  }
}

// ---- weight-chain precompute: P slices [48 cols x KTOT rows] f32 + rank-1 -
// Column-parallel: grid (10, 4). blockIdx.y = branch b (j=b+1), blockIdx.x =
// column group (4 of 40 cols). Each block evolves a 128x4 slice S <- W_k * S.
__global__ __launch_bounds__(256) void chains_k(
    const float* __restrict__ W_gcn, const float* __restrict__ b_gcn,
    const float* __restrict__ W_out, const float* __restrict__ b_out,
    float* __restrict__ Pf, float* __restrict__ rv) {
  __shared__ float T0[128 * 4];
  __shared__ float T1[128 * 4];
  const int b = blockIdx.y;          // 0..3
  const int j = b + 1;
  const int c0 = blockIdx.x * 4;     // col group base
  const int ks_all[4][4] = {{0, -1, -1, -1}, {1, 2, -1, -1}, {3, 4, 5, -1}, {6, 7, 8, 9}};
  const int t = threadIdx.x;
  const int lane = t & 63;
  const int wv = t >> 6;             // wave 0..3

  for (int idx = t; idx < 512; idx += 256) {
    int r = idx >> 2, c = idx & 3;
    T0[idx] = W_out[(size_t)(j * 128 + r) * 40 + c0 + c];
  }
  __syncthreads();
  float* Tc = T0;
  float* Tn = T1;
  for (int step = 0; step < j; ++step) {
    int kw = ks_all[b][j - 1 - step];
    {
      float s = b_gcn[kw * 128 + lane] * Tc[lane * 4 + wv] +
                b_gcn[kw * 128 + 64 + lane] * Tc[(64 + lane) * 4 + wv];
      for (int o = 32; o; o >>= 1) s += __shfl_down(s, o);
      if (lane == 0) atomicAdd(&rv[step * 40 + c0 + wv], s);
    }
    const float* W = W_gcn + (size_t)kw * 128 * 128;
    int r = t & 127;
    int ch = (t >> 7) << 1;          // 0 or 2
    float a0 = 0.f, a1 = 0.f;
    for (int k = 0; k < 128; k += 4) {
      float4 w4 = *(const float4*)&W[(size_t)r * 128 + k];
      a0 += w4.x * Tc[(k + 0) * 4 + ch] + w4.y * Tc[(k + 1) * 4 + ch] +
            w4.z * Tc[(k + 2) * 4 + ch] + w4.w * Tc[(k + 3) * 4 + ch];
      a1 += w4.x * Tc[(k + 0) * 4 + ch + 1] + w4.y * Tc[(k + 1) * 4 + ch + 1] +
            w4.z * Tc[(k + 2) * 4 + ch + 1] + w4.w * Tc[(k + 3) * 4 + ch + 1];
    }
    Tn[r * 4 + ch] = a0;
    Tn[r * 4 + ch + 1] = a1;
    __syncthreads();
    float* tmp = Tc; Tc = Tn; Tn = tmp;
  }
  for (int idx = t; idx < 512; idx += 256) {
    int r = idx >> 2, c = idx & 3;
    Pf[(size_t)(c0 + c) * KTOT + j * 128 + r] = Tc[idx];
  }
  if (b == 0) {
    for (int idx = t; idx < 512; idx += 256) {
      int r = idx >> 2, c = idx & 3;
      Pf[(size_t)(c0 + c) * KTOT + r] = W_out[(size_t)r * 40 + c0 + c];
    }
    if (blockIdx.x == 0 && t < 40) atomicAdd(&rv[t], b_out[t]);   // row_1 += b_out
  }
}

// ---- Wz collapse: Wzt[n][k] = bf16( sum_m W_in[k][m] * P(m,n) ), n=j*48+c --
// Also cz[n] = b_in . Pcol + rv[j][c]  (rank-1 bias terms fold into z_j).
// One block per n (240); threads over k (512).
__global__ __launch_bounds__(256) void wz_k(
    const float* __restrict__ W_in, const float* __restrict__ b_in,
    const float* __restrict__ Pf, const float* __restrict__ rv,
    unsigned short* __restrict__ Wzt, float* __restrict__ cz) {
  __shared__ float Pcol[128];
  __shared__ float bred[64];
  const int n = blockIdx.x;          // 0..239
  const int j = n / 48, c = n - j * 48;
  const int t = threadIdx.x;
  if (t < 128) Pcol[t] = Pf[(size_t)c * KTOT + j * 128 + t];
  __syncthreads();
  for (int k = t; k < F_IN; k += 256) {
    const float* wr = W_in + (size_t)k * 128;
    float s = 0.f;
    for (int m = 0; m < 128; m += 4) {
      float4 w4 = *(const float4*)&wr[m];
      s += w4.x * Pcol[m] + w4.y * Pcol[m + 1] +
           w4.z * Pcol[m + 2] + w4.w * Pcol[m + 3];
    }
    Wzt[(size_t)n * F_IN + k] = bf16_rne(s);
  }
  if (t < 64) bred[t] = b_in[t] * Pcol[t] + b_in[t + 64] * Pcol[t + 64];
  __syncthreads();
  if (t == 0) {
    float s = 0.f;
    for (int i = 0; i < 64; ++i) s += bred[i];
    float r = (j < 4 && c < 40) ? rv[j * 40 + c] : 0.f;
    cz[n] = s + r;
  }
}

// ------------- fused GEMM: Z[N,240] = bf16(x @ Wzt + cz) -------------------
// Round-1-verified 2-phase global_load_lds pipeline, 32x128 tile, BK=64,
// counted vmcnt(6), double-buffered 48KB LDS (3 blocks/CU). Run twice per
// row-block (blockIdx.x&1 = n-half); halves adjacent in dispatch so the
// second half's x-tile is L2/L3-hot.
__global__ __launch_bounds__(256)
__attribute__((amdgpu_waves_per_eu(3, 4)))
void gemm_xz_k(
    const float* __restrict__ A, const unsigned short* __restrict__ Wzt,
    const float* __restrict__ cz, unsigned short* __restrict__ Z, int M) {
  constexpr int K = F_IN, BK = 64, NT = K / BK;   // 8 k-stages
  __shared__ __align__(16) float As[2][32][64];          // 16 KB
  __shared__ __align__(16) unsigned short Bs[2][128][64]; // 32 KB
  const int t = threadIdx.x;
  const int lane = t & 63;
  const int w = t >> 6;
  const int q = lane >> 4;
  const int l15 = lane & 15;
  const int wm = w >> 1, wn = w & 1;
  const int nb = blockIdx.x & 1;
  const int m0 = (blockIdx.x >> 1) * 32;
  const int ncol0 = nb << 7;                      // 0 or 128

  // ---- per-lane pre-swizzled global source pointers ----
  const float* pA[2];
#pragma unroll
  for (int it = 0; it < 2; ++it) {
    int r = it * 16 + w * 4 + (lane >> 4);
    int gm = m0 + r; if (gm >= M) gm = M - 1;
    int c16 = lane & 15;
    int gcol = ((((c16 >> 1) ^ (r & 7)) << 3)) + ((c16 & 1) << 2);
    pA[it] = A + (size_t)gm * K + gcol;
  }
  const unsigned short* pB[4];
#pragma unroll
  for (int it = 0; it < 4; ++it) {
    int r = (it * 4 + w) * 8 + (lane >> 3);
    int c = lane & 7;
    pB[it] = Wzt + (size_t)(ncol0 + r) * K + ((c ^ (r & 7)) << 3);
  }

  f32x4 acc[4];
#pragma unroll
  for (int j = 0; j < 4; ++j) acc[j] = (f32x4){0.f, 0.f, 0.f, 0.f};

  auto STAGE = [&](int buf, int ks) {
#pragma unroll
    for (int it = 0; it < 2; ++it)
      GLOAD_LDS16(pA[it] + ks * BK, &As[buf][it * 16 + w * 4][0] + lane * 4);
#pragma unroll
    for (int it = 0; it < 4; ++it)
      GLOAD_LDS16(pB[it] + ks * BK, &Bs[buf][(it * 4 + w) * 8][0] + lane * 8);
  };

  auto COMPUTE = [&](int buf) {
#pragma unroll
    for (int kk = 0; kk < 2; ++kk) {
      int kc = (kk << 2) + q;
      int m = (wm << 4) + l15;
      const float* ap = &As[buf][m][(kc ^ (m & 7)) << 3];
      float4 f0 = *(const float4*)ap;
      float4 f1 = *(const float4*)(ap + 4);
      union { unsigned int u[4]; bf16x8 v; } ua;
      ua.u[0] = (unsigned int)bf16_rne(f0.x) | ((unsigned int)bf16_rne(f0.y) << 16);
      ua.u[1] = (unsigned int)bf16_rne(f0.z) | ((unsigned int)bf16_rne(f0.w) << 16);
      ua.u[2] = (unsigned int)bf16_rne(f1.x) | ((unsigned int)bf16_rne(f1.y) << 16);
      ua.u[3] = (unsigned int)bf16_rne(f1.z) | ((unsigned int)bf16_rne(f1.w) << 16);
      bf16x8 af = ua.v;
#pragma unroll
      for (int j = 0; j < 4; ++j) {
        int nn = (wn << 6) + (j << 4) + l15;
        bf16x8 bfr = *(const bf16x8*)&Bs[buf][nn][(kc ^ (nn & 7)) << 3];
        acc[j] = __builtin_amdgcn_mfma_f32_16x16x32_bf16(af, bfr, acc[j], 0, 0, 0);
      }
    }
  };

  STAGE(0, 0);
#pragma unroll
  for (int ts = 0; ts < NT; ++ts) {
    if (ts + 1 < NT) {
      STAGE((ts + 1) & 1, ts + 1);                       // 6 more in flight (12)
      asm volatile("s_waitcnt vmcnt(6)" ::: "memory");   // stage ts landed
    } else {
      asm volatile("s_waitcnt vmcnt(0)" ::: "memory");   // drain last stage
    }
    __builtin_amdgcn_s_barrier();
    __builtin_amdgcn_sched_barrier(0);   // no ds_read hoists above the barrier
    COMPUTE(ts & 1);
    __builtin_amdgcn_sched_barrier(0);
    __builtin_amdgcn_s_barrier();        // compute done before buf reuse
  }

#pragma unroll
  for (int j = 0; j < 4; ++j) {
    int col = (wn << 6) + (j << 4) + l15;
    int gcol = ncol0 + col;
    if (gcol >= ZW) continue;
    float bv = cz[gcol];
    int rb = m0 + (wm << 4) + (q << 2);
#pragma unroll
    for (int r = 0; r < 4; ++r) {
      int row = rb + r;
      if (row < M) Z[(size_t)row * ZW + gcol] = bf16_rne(acc[j][r] + bv);
    }
  }
}

// ---------------- Horner aggregation over 40-wide z blocks -----------------
// out = z0 + A(z1 + A(z2 + A(z3 + A z4)))   [z_k = Z block k, bf16]
// PASS 0: y1 = A*z4 + z3   (gather bf16 pairs from Z, write f32 y)
// PASS 1: y2 = A*y1 + z2   PASS 2: y3 = A*y2 + z1
// PASS 3: out = A*y3 + z0  (yout = out, f32 stride 40 — same format as y)
// Horner state kept f32 (no per-hop bf16 rounding). One node per wave;
// lanes 0..19 (bf16 dwords) / 0..39 (f32) cover the 40 columns; 8-edge
// unroll keeps 8 gathers in flight. Working set: y = 8 MB (半 L2), Z = 24 MB.
template <int PASS>
__global__ __launch_bounds__(256) void agg2_k(
    const int* __restrict__ rowp, const int2* __restrict__ csr,
    const float* __restrict__ yin, const unsigned short* __restrict__ Zs,
    float* __restrict__ yout, int n) {
  const int lane = threadIdx.x & 63;
  const int node = (blockIdx.x << 2) + (threadIdx.x >> 6);
  if (node >= n) return;
  const int beg = rowp[node], end = rowp[node + 1];
  if (PASS == 0) {
    if (lane >= 20) return;
    const unsigned int* Zd = (const unsigned int*)Zs;   // dword view, stride 120
    const unsigned int* in = Zd + 96 + lane;            // block4 (cols 192..)
    float ax = 0.f, ay = 0.f;
    int j = beg;
    for (; j + 7 < end; j += 8) {
      int2 e0 = csr[j],     e1 = csr[j + 1], e2 = csr[j + 2], e3 = csr[j + 3];
      int2 e4 = csr[j + 4], e5 = csr[j + 5], e6 = csr[j + 6], e7 = csr[j + 7];
      unsigned int v0 = in[(size_t)e0.x * 120], v1 = in[(size_t)e1.x * 120];
      unsigned int v2 = in[(size_t)e2.x * 120], v3 = in[(size_t)e3.x * 120];
      unsigned int v4 = in[(size_t)e4.x * 120], v5 = in[(size_t)e5.x * 120];
      unsigned int v6 = in[(size_t)e6.x * 120], v7 = in[(size_t)e7.x * 120];
      float w0 = __int_as_float(e0.y), w1 = __int_as_float(e1.y);
      float w2 = __int_as_float(e2.y), w3 = __int_as_float(e3.y);
      float w4 = __int_as_float(e4.y), w5 = __int_as_float(e5.y);
      float w6 = __int_as_float(e6.y), w7 = __int_as_float(e7.y);
      ax += w0 * bf16_lo_f(v0) + w1 * bf16_lo_f(v1) +
            w2 * bf16_lo_f(v2) + w3 * bf16_lo_f(v3);
      ay += w0 * bf16_hi_f(v0) + w1 * bf16_hi_f(v1) +
            w2 * bf16_hi_f(v2) + w3 * bf16_hi_f(v3);
      ax += w4 * bf16_lo_f(v4) + w5 * bf16_lo_f(v5) +
            w6 * bf16_lo_f(v6) + w7 * bf16_lo_f(v7);
      ay += w4 * bf16_hi_f(v4) + w5 * bf16_hi_f(v5) +
            w6 * bf16_hi_f(v6) + w7 * bf16_hi_f(v7);
    }
    for (; j < end; ++j) {
      int2 e = csr[j];
      float w = __int_as_float(e.y);
      unsigned int v = in[(size_t)e.x * 120];
      ax += w * bf16_lo_f(v);
      ay += w * bf16_hi_f(v);
    }
    unsigned int z = Zd[(size_t)node * 120 + 72 + lane];   // block3
    float2 o;
    o.x = ax + bf16_lo_f(z);
    o.y = ay + bf16_hi_f(z);
    *(float2*)&yout[(size_t)node * 40 + (lane << 1)] = o;
  } else {
    if (lane >= 40) return;
    const float* in = yin + lane;
    float a = 0.f;
    int j = beg;
    for (; j + 7 < end; j += 8) {
      int2 e0 = csr[j],     e1 = csr[j + 1], e2 = csr[j + 2], e3 = csr[j + 3];
      int2 e4 = csr[j + 4], e5 = csr[j + 5], e6 = csr[j + 6], e7 = csr[j + 7];
      float g0 = in[(size_t)e0.x * 40], g1 = in[(size_t)e1.x * 40];
      float g2 = in[(size_t)e2.x * 40], g3 = in[(size_t)e3.x * 40];
      float g4 = in[(size_t)e4.x * 40], g5 = in[(size_t)e5.x * 40];
      float g6 = in[(size_t)e6.x * 40], g7 = in[(size_t)e7.x * 40];
      float w0 = __int_as_float(e0.y), w1 = __int_as_float(e1.y);
      float w2 = __int_as_float(e2.y), w3 = __int_as_float(e3.y);
      float w4 = __int_as_float(e4.y), w5 = __int_as_float(e5.y);
      float w6 = __int_as_float(e6.y), w7 = __int_as_float(e7.y);
      a += w0 * g0 + w1 * g1 + w2 * g2 + w3 * g3;
      a += w4 * g4 + w5 * g5 + w6 * g6 + w7 * g7;
    }
    for (; j < end; ++j) {
      int2 e = csr[j];
      a += __int_as_float(e.y) * in[(size_t)e.x * 40];
    }
    float zv = bf16_lo_f((unsigned int)Zs[(size_t)node * ZW + (3 - PASS) * 48 + lane]);
    yout[(size_t)node * 40 + lane] = a + zv;
  }
}

// ------------------------------- launcher ----------------------------------

extern "C" void kernel_launch(void* const* d_in, const int* in_sizes, int n_in,
                              void* d_out, int out_size, void* d_ws, size_t ws_size,
                              hipStream_t stream) {
  const float* x     = (const float*)d_in[0];
  const int*   eidx  = (const int*)  d_in[1];
  const float* ew    = (const float*)d_in[2];
  const float* W_in  = (const float*)d_in[3];
  const float* b_in  = (const float*)d_in[4];
  const float* W_gcn = (const float*)d_in[5];
  const float* b_gcn = (const float*)d_in[6];
  const float* W_out = (const float*)d_in[7];
  const float* b_out = (const float*)d_in[8];
  float* out = (float*)d_out;

  const int* src = eidx;
  const int* dst = eidx + N_EDGES;

  char* ws = (char*)d_ws;
  size_t off = 0;
  auto alloc = [&](size_t bytes) -> void* {
    void* p = ws + off;
    off += (bytes + 255) & ~(size_t)255;
    return p;
  };
  unsigned long long* acc = (unsigned long long*)alloc((size_t)N_NODES * 8);
  int*   pos    = (int*)  alloc((size_t)N_EDGES * 4);
  int*   cnt    = (int*)  alloc((size_t)N_NODES * 4);
  int*   rowp   = (int*)  alloc((size_t)(N_NODES + 1) * 4);
  float* dinv   = (float*)alloc((size_t)N_NODES * 4);
  int*   bsum   = (int*)  alloc((size_t)256 * 4);
  int2*  csr    = (int2*) alloc((size_t)TOT_E * 8);
  float* Pf     = (float*)alloc((size_t)48 * KTOT * 4);
  unsigned short* Wzt = (unsigned short*)alloc((size_t)NZP * F_IN * 2);
  float* cz     = (float*)alloc((size_t)NZP * 4);
  unsigned short* Z = (unsigned short*)alloc((size_t)N_NODES * ZW * 2);
  float* ya     = (float*)alloc((size_t)N_NODES * 40 * 4);
  float* yb     = (float*)alloc((size_t)N_NODES * 40 * 4);
  float* rv     = (float*)alloc((size_t)4 * 40 * 4);
  (void)ws_size; (void)in_sizes; (void)n_in; (void)out_size;

  dim3 b256(256);
  const int NB = (N_NODES + 255) / 256;
  const int GBZ = ((N_NODES + 31) / 32) * 2;  // 3126 blocks (2 n-halves)
  const int AB = (N_NODES + 3) / 4;

  hipMemsetAsync(acc, 0, (size_t)N_NODES * 8, stream);
  hipMemsetAsync(rv, 0, (size_t)4 * 40 * 4, stream);
  hipMemsetAsync(Pf, 0, (size_t)48 * KTOT * 4, stream);   // pad cols 40..47 = 0
  hipMemsetAsync(Wzt, 0, (size_t)NZP * F_IN * 2, stream); // pad rows 240..255 = 0
  hipMemsetAsync(cz, 0, (size_t)NZP * 4, stream);

  edge_pass1_k<<<(N_EDGES + 255) / 256, b256, 0, stream>>>(dst, ew, acc, pos, N_EDGES);
  node_pass_k<<<NB, b256, 0, stream>>>(acc, dinv, cnt, N_NODES);
  block_reduce_k<<<NB, b256, 0, stream>>>(cnt, bsum, N_NODES);
  scan_bsums_k<<<1, b256, 0, stream>>>(bsum, NB);
  scan_write_k<<<NB, b256, 0, stream>>>(cnt, bsum, rowp, N_NODES);
  scatter2_k<<<(TOT_E + 255) / 256, b256, 0, stream>>>(src, dst, ew, pos, dinv, rowp,
                                                       csr, N_EDGES, N_NODES);

  chains_k<<<dim3(10, 4), b256, 0, stream>>>(W_gcn, b_gcn, W_out, b_out, Pf, rv);
  wz_k<<<ZW, b256, 0, stream>>>(W_in, b_in, Pf, rv, Wzt, cz);

  // Z[N,240] = bf16(x @ Wzt + cz)
  gemm_xz_k<<<GBZ, b256, 0, stream>>>(x, Wzt, cz, Z, N_NODES);

  // Horner: out = z0 + A(z1 + A(z2 + A(z3 + A z4)))
  agg2_k<0><<<AB, b256, 0, stream>>>(rowp, csr, nullptr, Z, ya, N_NODES);
  agg2_k<1><<<AB, b256, 0, stream>>>(rowp, csr, ya, Z, yb, N_NODES);
  agg2_k<2><<<AB, b256, 0, stream>>>(rowp, csr, yb, Z, ya, N_NODES);
  agg2_k<3><<<AB, b256, 0, stream>>>(rowp, csr, ya, Z, out, N_NODES);
}

// Round 3
// 434.056 us; speedup vs baseline: 1.1138x; 1.1138x over previous
//
#include <hip/hip_runtime.h>
#include <cstdint>
#include <cstddef>

#define N_NODES 50000
#define N_EDGES 800000
#define F_IN    512
#define H_DIM   128
#define C_OUT   40
#define TOT_E   (N_EDGES + N_NODES)
#define KTOT    640             // P rows: h | u1 | u2 | u3 | u4
#define ZW      240             // Z row width: 5 blocks x 48
#define NZP     256             // Wzt rows padded to 256

typedef __attribute__((ext_vector_type(8))) __bf16 bf16x8;
typedef __attribute__((ext_vector_type(4))) float f32x4;

__device__ __forceinline__ unsigned short bf16_rne(float f) {
  unsigned int u = __float_as_uint(f);
  u += 0x7fffu + ((u >> 16) & 1u);
  return (unsigned short)(u >> 16);
}
__device__ __forceinline__ float bf16_lo_f(unsigned int u) { return __uint_as_float(u << 16); }
__device__ __forceinline__ float bf16_hi_f(unsigned int u) { return __uint_as_float(u & 0xffff0000u); }

// async global->LDS, 16B per lane; dest must be linear (base + lane*16)
#define GLOAD_LDS16(gp, lp)                                                        \
  __builtin_amdgcn_global_load_lds(                                                \
      (const __attribute__((address_space(1))) void*)(gp),                         \
      (__attribute__((address_space(3))) void*)(lp), 16, 0, 0)

// ----------------------------- setup kernels -------------------------------
// Single u64 atomic per edge: bits [40..63] = count, [0..39] = 2^-24 fixed-pt
// weighted degree. Returned old count = slot of edge in its dst bucket.

__global__ void edge_pass1_k(const int* __restrict__ dst, const float* __restrict__ ew,
                             unsigned long long* __restrict__ acc,
                             int* __restrict__ pos, int e) {
  int i = blockIdx.x * blockDim.x + threadIdx.x;
  if (i < e) {
    int d = dst[i];
    unsigned long long v = (1ull << 40) |
        (unsigned long long)(ew[i] * 16777216.0f + 0.5f);
    unsigned long long old = atomicAdd(&acc[d], v);
    pos[i] = (int)(old >> 40);
  }
}

__global__ void node_pass_k(const unsigned long long* __restrict__ acc,
                            float* __restrict__ dinv, int* __restrict__ cnt, int n) {
  int i = blockIdx.x * blockDim.x + threadIdx.x;
  if (i < n) {
    unsigned long long a = acc[i];
    double dfix = (double)(a & 0xFFFFFFFFFFull);
    float deg = (float)(dfix * (1.0 / 16777216.0) + 1.0);   // +1 self-loop
    dinv[i] = rsqrtf(deg);
    cnt[i] = (int)(a >> 40) + 1;                            // +1 self-loop
  }
}

__global__ __launch_bounds__(256) void block_reduce_k(const int* __restrict__ cnt,
                                                      int* bsum, int n) {
  __shared__ int s[256];
  int t = threadIdx.x;
  int i = blockIdx.x * 256 + t;
  s[t] = (i < n) ? cnt[i] : 0;
  __syncthreads();
  for (int off = 128; off; off >>= 1) {
    if (t < off) s[t] += s[t + off];
    __syncthreads();
  }
  if (t == 0) bsum[blockIdx.x] = s[0];
}

__global__ __launch_bounds__(256) void scan_bsums_k(int* bsum, int nb) {
  __shared__ int s[256];
  int t = threadIdx.x;
  s[t] = (t < nb) ? bsum[t] : 0;
  __syncthreads();
  for (int off = 1; off < 256; off <<= 1) {
    int v = (t >= off) ? s[t - off] : 0;
    __syncthreads();
    s[t] += v;
    __syncthreads();
  }
  if (t < nb) bsum[t] = (t == 0) ? 0 : s[t - 1];
}

__global__ __launch_bounds__(256) void scan_write_k(const int* __restrict__ cnt,
                                                    const int* __restrict__ bsum,
                                                    int* row_ptr, int n) {
  __shared__ int s[256];
  int t = threadIdx.x;
  int i = blockIdx.x * 256 + t;
  int c = (i < n) ? cnt[i] : 0;
  s[t] = c;
  __syncthreads();
  for (int off = 1; off < 256; off <<= 1) {
    int v = (t >= off) ? s[t - off] : 0;
    __syncthreads();
    s[t] += v;
    __syncthreads();
  }
  int ex = bsum[blockIdx.x] + ((t == 0) ? 0 : s[t - 1]);
  if (i < n) row_ptr[i] = ex;
  if (i == n - 1) row_ptr[n] = ex + c;
}

__global__ void scatter2_k(const int* __restrict__ src, const int* __restrict__ dst,
                           const float* __restrict__ ew, const int* __restrict__ pos,
                           const float* __restrict__ dinv, const int* __restrict__ rowp,
                           int2* __restrict__ csr, int e, int n) {
  int i = blockIdx.x * blockDim.x + threadIdx.x;
  if (i < e) {
    int s = src[i], d = dst[i];
    float w = dinv[s] * ew[i] * dinv[d];
    csr[rowp[d] + pos[i]] = make_int2(s, __float_as_int(w));
  } else if (i < e + n) {
    int v = i - e;
    float di = dinv[v];
    csr[rowp[v + 1] - 1] = make_int2(v, __float_as_int(di * di));  // self-loop last
  }
}

// ---- weight-chain precompute: P slices [48 cols x KTOT rows] f32 + rank-1 -
__global__ __launch_bounds__(256) void chains_k(
    const float* __restrict__ W_gcn, const float* __restrict__ b_gcn,
    const float* __restrict__ W_out, const float* __restrict__ b_out,
    float* __restrict__ Pf, float* __restrict__ rv) {
  __shared__ float T0[128 * 4];
  __shared__ float T1[128 * 4];
  const int b = blockIdx.y;          // 0..3
  const int j = b + 1;
  const int c0 = blockIdx.x * 4;     // col group base
  const int ks_all[4][4] = {{0, -1, -1, -1}, {1, 2, -1, -1}, {3, 4, 5, -1}, {6, 7, 8, 9}};
  const int t = threadIdx.x;
  const int lane = t & 63;
  const int wv = t >> 6;             // wave 0..3

  for (int idx = t; idx < 512; idx += 256) {
    int r = idx >> 2, c = idx & 3;
    T0[idx] = W_out[(size_t)(j * 128 + r) * 40 + c0 + c];
  }
  __syncthreads();
  float* Tc = T0;
  float* Tn = T1;
  for (int step = 0; step < j; ++step) {
    int kw = ks_all[b][j - 1 - step];
    {
      float s = b_gcn[kw * 128 + lane] * Tc[lane * 4 + wv] +
                b_gcn[kw * 128 + 64 + lane] * Tc[(64 + lane) * 4 + wv];
      for (int o = 32; o; o >>= 1) s += __shfl_down(s, o);
      if (lane == 0) atomicAdd(&rv[step * 40 + c0 + wv], s);
    }
    const float* W = W_gcn + (size_t)kw * 128 * 128;
    int r = t & 127;
    int ch = (t >> 7) << 1;          // 0 or 2
    float a0 = 0.f, a1 = 0.f;
    for (int k = 0; k < 128; k += 4) {
      float4 w4 = *(const float4*)&W[(size_t)r * 128 + k];
      a0 += w4.x * Tc[(k + 0) * 4 + ch] + w4.y * Tc[(k + 1) * 4 + ch] +
            w4.z * Tc[(k + 2) * 4 + ch] + w4.w * Tc[(k + 3) * 4 + ch];
      a1 += w4.x * Tc[(k + 0) * 4 + ch + 1] + w4.y * Tc[(k + 1) * 4 + ch + 1] +
            w4.z * Tc[(k + 2) * 4 + ch + 1] + w4.w * Tc[(k + 3) * 4 + ch + 1];
    }
    Tn[r * 4 + ch] = a0;
    Tn[r * 4 + ch + 1] = a1;
    __syncthreads();
    float* tmp = Tc; Tc = Tn; Tn = tmp;
  }
  for (int idx = t; idx < 512; idx += 256) {
    int r = idx >> 2, c = idx & 3;
    Pf[(size_t)(c0 + c) * KTOT + j * 128 + r] = Tc[idx];
  }
  if (b == 0) {
    for (int idx = t; idx < 512; idx += 256) {
      int r = idx >> 2, c = idx & 3;
      Pf[(size_t)(c0 + c) * KTOT + r] = W_out[(size_t)r * 40 + c0 + c];
    }
    if (blockIdx.x == 0 && t < 40) atomicAdd(&rv[t], b_out[t]);   // row_1 += b_out
  }
}

// ---- Wz collapse: Wzt[n][k] = bf16( sum_m W_in[k][m] * P(m,n) ), n=j*48+c --
// Also cz[n] = b_in . Pcol + rv[j][c]  (rank-1 bias terms fold into z_j).
__global__ __launch_bounds__(256) void wz_k(
    const float* __restrict__ W_in, const float* __restrict__ b_in,
    const float* __restrict__ Pf, const float* __restrict__ rv,
    unsigned short* __restrict__ Wzt, float* __restrict__ cz) {
  __shared__ float Pcol[128];
  __shared__ float bred[64];
  const int n = blockIdx.x;          // 0..239
  const int j = n / 48, c = n - j * 48;
  const int t = threadIdx.x;
  if (t < 128) Pcol[t] = Pf[(size_t)c * KTOT + j * 128 + t];
  __syncthreads();
  for (int k = t; k < F_IN; k += 256) {
    const float* wr = W_in + (size_t)k * 128;
    float s = 0.f;
    for (int m = 0; m < 128; m += 4) {
      float4 w4 = *(const float4*)&wr[m];
      s += w4.x * Pcol[m] + w4.y * Pcol[m + 1] +
           w4.z * Pcol[m + 2] + w4.w * Pcol[m + 3];
    }
    Wzt[(size_t)n * F_IN + k] = bf16_rne(s);
  }
  if (t < 64) bred[t] = b_in[t] * Pcol[t] + b_in[t + 64] * Pcol[t + 64];
  __syncthreads();
  if (t == 0) {
    float s = 0.f;
    for (int i = 0; i < 64; ++i) s += bred[i];
    float r = (j < 4 && c < 40) ? rv[j * 40 + c] : 0.f;
    cz[n] = s + r;
  }
}

// ------------- fused GEMM: Z[N,240] = bf16(x @ Wzt + cz) -------------------
// Round-3: single-pass 64x256 tile, BK=32, NT=16. Same verified 2-phase
// global_load_lds pipeline (6 insts/wave/stage, vmcnt(6), double-buffered
// 48KB LDS = 3 blocks/CU). Halves block-steps vs round-2 (12512 vs 25008)
// and reads x exactly once. XOR swizzle: A 32B-granular ^(r&3),
// B 16B-granular ^(r&3) (4-way LDS read conflict, acceptable).
__global__ __launch_bounds__(256)
__attribute__((amdgpu_waves_per_eu(3, 4)))
void gemm_xz_k(
    const float* __restrict__ A, const unsigned short* __restrict__ Wzt,
    const float* __restrict__ cz, unsigned short* __restrict__ Z, int M) {
  constexpr int K = F_IN, BK = 32, NT = K / BK;   // 16 k-stages
  __shared__ __align__(16) float As[2][64][32];           // 16 KB
  __shared__ __align__(16) unsigned short Bs[2][256][32]; // 32 KB
  const int t = threadIdx.x;
  const int lane = t & 63;
  const int w = t >> 6;
  const int q = lane >> 4;
  const int l15 = lane & 15;
  const int wm = w >> 1, wn = w & 1;
  const int m0 = blockIdx.x * 64;

  // ---- per-lane pre-swizzled global source pointers ----
  // A: inst it in {0,1}: rows r = (w*2+it)*8 + (lane>>3), chunk16 c = lane&7.
  // LDS 32B pair p of row r holds global pair p ^ (r&3).
  const float* pA[2];
#pragma unroll
  for (int it = 0; it < 2; ++it) {
    int r = (w * 2 + it) * 8 + (lane >> 3);
    int gm = m0 + r; if (gm >= M) gm = M - 1;
    int c = lane & 7;
    int gcol = ((((c >> 1) ^ (r & 3)) << 3)) + ((c & 1) << 2);
    pA[it] = A + (size_t)gm * K + gcol;
  }
  // B: inst it in {0..3}: rows r = (w*4+it)*16 + (lane>>2), chunk16 c = lane&3.
  // LDS 16B chunk c of row r holds global chunk c ^ (r&3).
  const unsigned short* pB[4];
#pragma unroll
  for (int it = 0; it < 4; ++it) {
    int r = (w * 4 + it) * 16 + (lane >> 2);
    int c = lane & 3;
    pB[it] = Wzt + (size_t)r * K + ((c ^ (r & 3)) << 3);
  }

  f32x4 acc[2][8];
#pragma unroll
  for (int i = 0; i < 2; ++i)
#pragma unroll
    for (int j = 0; j < 8; ++j) acc[i][j] = (f32x4){0.f, 0.f, 0.f, 0.f};

  auto STAGE = [&](int buf, int ks) {
#pragma unroll
    for (int it = 0; it < 2; ++it)
      GLOAD_LDS16(pA[it] + ks * BK, &As[buf][(w * 2 + it) * 8][0] + lane * 4);
#pragma unroll
    for (int it = 0; it < 4; ++it)
      GLOAD_LDS16(pB[it] + ks * BK, &Bs[buf][(w * 4 + it) * 16][0] + lane * 8);
  };

  auto COMPUTE = [&](int buf) {
    bf16x8 af[2];
#pragma unroll
    for (int i = 0; i < 2; ++i) {
      int m = (wm << 5) + (i << 4) + l15;
      const float* ap = &As[buf][m][(q ^ (m & 3)) << 3];
      float4 f0 = *(const float4*)ap;
      float4 f1 = *(const float4*)(ap + 4);
      union { unsigned int u[4]; bf16x8 v; } ua;
      ua.u[0] = (unsigned int)bf16_rne(f0.x) | ((unsigned int)bf16_rne(f0.y) << 16);
      ua.u[1] = (unsigned int)bf16_rne(f0.z) | ((unsigned int)bf16_rne(f0.w) << 16);
      ua.u[2] = (unsigned int)bf16_rne(f1.x) | ((unsigned int)bf16_rne(f1.y) << 16);
      ua.u[3] = (unsigned int)bf16_rne(f1.z) | ((unsigned int)bf16_rne(f1.w) << 16);
      af[i] = ua.v;
    }
#pragma unroll
    for (int j = 0; j < 8; ++j) {
      int nn = (wn << 7) + (j << 4) + l15;
      bf16x8 bfr = *(const bf16x8*)&Bs[buf][nn][(q ^ (nn & 3)) << 3];
#pragma unroll
      for (int i = 0; i < 2; ++i)
        acc[i][j] = __builtin_amdgcn_mfma_f32_16x16x32_bf16(af[i], bfr, acc[i][j], 0, 0, 0);
    }
  };

  STAGE(0, 0);
#pragma unroll
  for (int ts = 0; ts < NT; ++ts) {
    if (ts + 1 < NT) {
      STAGE((ts + 1) & 1, ts + 1);                       // 6 more in flight (12)
      asm volatile("s_waitcnt vmcnt(6)" ::: "memory");   // stage ts landed
    } else {
      asm volatile("s_waitcnt vmcnt(0)" ::: "memory");   // drain last stage
    }
    __builtin_amdgcn_s_barrier();
    __builtin_amdgcn_sched_barrier(0);   // no ds_read hoists above the barrier
    COMPUTE(ts & 1);
    __builtin_amdgcn_sched_barrier(0);
    __builtin_amdgcn_s_barrier();        // compute done before buf reuse
  }

#pragma unroll
  for (int j = 0; j < 8; ++j) {
    int gcol = (wn << 7) + (j << 4) + l15;
    if (gcol >= ZW) continue;
    float bv = cz[gcol];
#pragma unroll
    for (int i = 0; i < 2; ++i) {
      int rb = m0 + (wm << 5) + (i << 4) + (q << 2);
#pragma unroll
      for (int r = 0; r < 4; ++r) {
        int row = rb + r;
        if (row < M) Z[(size_t)row * ZW + gcol] = bf16_rne(acc[i][j][r] + bv);
      }
    }
  }
}

// ---------------- Horner aggregation over 40-wide z blocks -----------------
// out = z0 + A(z1 + A(z2 + A(z3 + A z4)))   [z_k = Z block k, bf16]
// PASS 0: y1 = A*z4 + z3   PASS 1: y2 = A*y1 + z2
// PASS 2: y3 = A*y2 + z1   PASS 3: out = A*y3 + z0
// Horner state f32 [N][40] (numerics identical to round-2).
// Round-3: 3 nodes per wave (lane groups of 20; lanes 60-63 idle) -> 3x the
// gather parallelism per wave, grid 12500 -> 4167 blocks. Divergence between
// the 3 groups handled by __any loops (mean deg 17, max-of-3 ~ 22).
template <int PASS>
__global__ __launch_bounds__(256) void agg2_k(
    const int* __restrict__ rowp, const int2* __restrict__ csr,
    const float* __restrict__ yin, const unsigned int* __restrict__ Zd,
    float* __restrict__ yout, int n) {
  const int lane = threadIdx.x & 63;
  const int wv = threadIdx.x >> 6;
  const int g = lane / 20;            // group 0..2 (g==3: idle)
  const int gl = lane - g * 20;       // 0..19 (dword-col within node)
  const int node = ((blockIdx.x << 2) + wv) * 3 + g;
  const bool alive = (g < 3) && (node < n);
  int beg = 0, end = 0;
  if (alive) { beg = rowp[node]; end = rowp[node + 1]; }
  float ax = 0.f, ay = 0.f;
  int j = beg;
  if (PASS == 0) {
    const unsigned int* in = Zd + 96 + gl;    // Z block4, dword stride 120
    while (__any(j + 8 <= end)) {
      if (j + 8 <= end) {
        int2 e0 = csr[j],     e1 = csr[j + 1], e2 = csr[j + 2], e3 = csr[j + 3];
        int2 e4 = csr[j + 4], e5 = csr[j + 5], e6 = csr[j + 6], e7 = csr[j + 7];
        unsigned int v0 = in[(size_t)e0.x * 120], v1 = in[(size_t)e1.x * 120];
        unsigned int v2 = in[(size_t)e2.x * 120], v3 = in[(size_t)e3.x * 120];
        unsigned int v4 = in[(size_t)e4.x * 120], v5 = in[(size_t)e5.x * 120];
        unsigned int v6 = in[(size_t)e6.x * 120], v7 = in[(size_t)e7.x * 120];
        float w0 = __int_as_float(e0.y), w1 = __int_as_float(e1.y);
        float w2 = __int_as_float(e2.y), w3 = __int_as_float(e3.y);
        float w4 = __int_as_float(e4.y), w5 = __int_as_float(e5.y);
        float w6 = __int_as_float(e6.y), w7 = __int_as_float(e7.y);
        ax += w0 * bf16_lo_f(v0) + w1 * bf16_lo_f(v1) +
              w2 * bf16_lo_f(v2) + w3 * bf16_lo_f(v3);
        ay += w0 * bf16_hi_f(v0) + w1 * bf16_hi_f(v1) +
              w2 * bf16_hi_f(v2) + w3 * bf16_hi_f(v3);
        ax += w4 * bf16_lo_f(v4) + w5 * bf16_lo_f(v5) +
              w6 * bf16_lo_f(v6) + w7 * bf16_lo_f(v7);
        ay += w4 * bf16_hi_f(v4) + w5 * bf16_hi_f(v5) +
              w6 * bf16_hi_f(v6) + w7 * bf16_hi_f(v7);
        j += 8;
      }
    }
    while (__any(j < end)) {
      if (j < end) {
        int2 e = csr[j];
        float w = __int_as_float(e.y);
        unsigned int v = in[(size_t)e.x * 120];
        ax += w * bf16_lo_f(v);
        ay += w * bf16_hi_f(v);
        ++j;
      }
    }
  } else {
    const float* in = yin + (gl << 1);        // f32 pair, row stride 40
    while (__any(j + 8 <= end)) {
      if (j + 8 <= end) {
        int2 e0 = csr[j],     e1 = csr[j + 1], e2 = csr[j + 2], e3 = csr[j + 3];
        int2 e4 = csr[j + 4], e5 = csr[j + 5], e6 = csr[j + 6], e7 = csr[j + 7];
        float2 v0 = *(const float2*)&in[(size_t)e0.x * 40];
        float2 v1 = *(const float2*)&in[(size_t)e1.x * 40];
        float2 v2 = *(const float2*)&in[(size_t)e2.x * 40];
        float2 v3 = *(const float2*)&in[(size_t)e3.x * 40];
        float2 v4 = *(const float2*)&in[(size_t)e4.x * 40];
        float2 v5 = *(const float2*)&in[(size_t)e5.x * 40];
        float2 v6 = *(const float2*)&in[(size_t)e6.x * 40];
        float2 v7 = *(const float2*)&in[(size_t)e7.x * 40];
        float w0 = __int_as_float(e0.y), w1 = __int_as_float(e1.y);
        float w2 = __int_as_float(e2.y), w3 = __int_as_float(e3.y);
        float w4 = __int_as_float(e4.y), w5 = __int_as_float(e5.y);
        float w6 = __int_as_float(e6.y), w7 = __int_as_float(e7.y);
        ax += w0 * v0.x + w1 * v1.x + w2 * v2.x + w3 * v3.x;
        ay += w0 * v0.y + w1 * v1.y + w2 * v2.y + w3 * v3.y;
        ax += w4 * v4.x + w5 * v5.x + w6 * v6.x + w7 * v7.x;
        ay += w4 * v4.y + w5 * v5.y + w6 * v6.y + w7 * v7.y;
        j += 8;
      }
    }
    while (__any(j < end)) {
      if (j < end) {
        int2 e = csr[j];
        float w = __int_as_float(e.y);
        float2 v = *(const float2*)&in[(size_t)e.x * 40];
        ax += w * v.x;
        ay += w * v.y;
        ++j;
      }
    }
  }
  if (alive) {
    unsigned int z = Zd[(size_t)node * 120 + (3 - PASS) * 24 + gl];
    float2 o;
    o.x = ax + bf16_lo_f(z);
    o.y = ay + bf16_hi_f(z);
    *(float2*)&yout[(size_t)node * 40 + (gl << 1)] = o;
  }
}

// ------------------------------- launcher ----------------------------------

extern "C" void kernel_launch(void* const* d_in, const int* in_sizes, int n_in,
                              void* d_out, int out_size, void* d_ws, size_t ws_size,
                              hipStream_t stream) {
  const float* x     = (const float*)d_in[0];
  const int*   eidx  = (const int*)  d_in[1];
  const float* ew    = (const float*)d_in[2];
  const float* W_in  = (const float*)d_in[3];
  const float* b_in  = (const float*)d_in[4];
  const float* W_gcn = (const float*)d_in[5];
  const float* b_gcn = (const float*)d_in[6];
  const float* W_out = (const float*)d_in[7];
  const float* b_out = (const float*)d_in[8];
  float* out = (float*)d_out;

  const int* src = eidx;
  const int* dst = eidx + N_EDGES;

  char* ws = (char*)d_ws;
  size_t off = 0;
  auto alloc = [&](size_t bytes) -> void* {
    void* p = ws + off;
    off += (bytes + 255) & ~(size_t)255;
    return p;
  };
  unsigned long long* acc = (unsigned long long*)alloc((size_t)N_NODES * 8);
  int*   pos    = (int*)  alloc((size_t)N_EDGES * 4);
  int*   cnt    = (int*)  alloc((size_t)N_NODES * 4);
  int*   rowp   = (int*)  alloc((size_t)(N_NODES + 1) * 4);
  float* dinv   = (float*)alloc((size_t)N_NODES * 4);
  int*   bsum   = (int*)  alloc((size_t)256 * 4);
  int2*  csr    = (int2*) alloc((size_t)TOT_E * 8);
  float* Pf     = (float*)alloc((size_t)48 * KTOT * 4);
  unsigned short* Wzt = (unsigned short*)alloc((size_t)NZP * F_IN * 2);
  float* cz     = (float*)alloc((size_t)NZP * 4);
  unsigned short* Z = (unsigned short*)alloc((size_t)N_NODES * ZW * 2);
  float* ya     = (float*)alloc((size_t)N_NODES * 40 * 4);
  float* yb     = (float*)alloc((size_t)N_NODES * 40 * 4);
  float* rv     = (float*)alloc((size_t)4 * 40 * 4);
  (void)ws_size; (void)in_sizes; (void)n_in; (void)out_size;

  dim3 b256(256);
  const int NB = (N_NODES + 255) / 256;
  const int GBZ = (N_NODES + 63) / 64;        // 782 blocks, single pass
  const int AB3 = (N_NODES + 11) / 12;        // 4167 blocks (12 nodes each)
  const unsigned int* Zd = (const unsigned int*)Z;

  hipMemsetAsync(acc, 0, (size_t)N_NODES * 8, stream);
  hipMemsetAsync(rv, 0, (size_t)4 * 40 * 4, stream);
  hipMemsetAsync(Pf, 0, (size_t)48 * KTOT * 4, stream);   // pad cols 40..47 = 0
  hipMemsetAsync(Wzt, 0, (size_t)NZP * F_IN * 2, stream); // pad rows 240..255 = 0
  hipMemsetAsync(cz, 0, (size_t)NZP * 4, stream);

  edge_pass1_k<<<(N_EDGES + 255) / 256, b256, 0, stream>>>(dst, ew, acc, pos, N_EDGES);
  node_pass_k<<<NB, b256, 0, stream>>>(acc, dinv, cnt, N_NODES);
  block_reduce_k<<<NB, b256, 0, stream>>>(cnt, bsum, N_NODES);
  scan_bsums_k<<<1, b256, 0, stream>>>(bsum, NB);
  scan_write_k<<<NB, b256, 0, stream>>>(cnt, bsum, rowp, N_NODES);
  scatter2_k<<<(TOT_E + 255) / 256, b256, 0, stream>>>(src, dst, ew, pos, dinv, rowp,
                                                       csr, N_EDGES, N_NODES);

  chains_k<<<dim3(10, 4), b256, 0, stream>>>(W_gcn, b_gcn, W_out, b_out, Pf, rv);
  wz_k<<<ZW, b256, 0, stream>>>(W_in, b_in, Pf, rv, Wzt, cz);

  // Z[N,240] = bf16(x @ Wzt + cz)
  gemm_xz_k<<<GBZ, b256, 0, stream>>>(x, Wzt, cz, Z, N_NODES);

  // Horner: out = z0 + A(z1 + A(z2 + A(z3 + A z4)))
  agg2_k<0><<<AB3, b256, 0, stream>>>(rowp, csr, nullptr, Zd, ya, N_NODES);
  agg2_k<1><<<AB3, b256, 0, stream>>>(rowp, csr, ya, Zd, yb, N_NODES);
  agg2_k<2><<<AB3, b256, 0, stream>>>(rowp, csr, yb, Zd, ya, N_NODES);
  agg2_k<3><<<AB3, b256, 0, stream>>>(rowp, csr, ya, Zd, out, N_NODES);
}

// Round 4
// 425.032 us; speedup vs baseline: 1.1374x; 1.0212x over previous
//
#include <hip/hip_runtime.h>
#include <cstdint>
#include <cstddef>

#define N_NODES 50000
#define N_EDGES 800000
#define F_IN    512
#define H_DIM   128
#define C_OUT   40
#define TOT_E   (N_EDGES + N_NODES)
#define KTOT    640             // P rows: h | u1 | u2 | u3 | u4
#define ZW      240             // Z row width: 5 blocks x 48
#define NZP     256             // Wzt rows padded to 256

typedef __attribute__((ext_vector_type(8))) __bf16 bf16x8;
typedef __attribute__((ext_vector_type(4))) float f32x4;

__device__ __forceinline__ unsigned short bf16_rne(float f) {
  unsigned int u = __float_as_uint(f);
  u += 0x7fffu + ((u >> 16) & 1u);
  return (unsigned short)(u >> 16);
}
__device__ __forceinline__ float bf16_lo_f(unsigned int u) { return __uint_as_float(u << 16); }
__device__ __forceinline__ float bf16_hi_f(unsigned int u) { return __uint_as_float(u & 0xffff0000u); }

// async global->LDS, 16B per lane; dest must be linear (base + lane*16)
#define GLOAD_LDS16(gp, lp)                                                        \
  __builtin_amdgcn_global_load_lds(                                                \
      (const __attribute__((address_space(1))) void*)(gp),                         \
      (__attribute__((address_space(3))) void*)(lp), 16, 0, 0)

// ----------------------------- setup kernels -------------------------------
// Single u64 atomic per edge: bits [40..63] = count, [0..39] = 2^-24 fixed-pt
// weighted degree. Returned old count = slot of edge in its dst bucket.

__global__ void edge_pass1_k(const int* __restrict__ dst, const float* __restrict__ ew,
                             unsigned long long* __restrict__ acc,
                             int* __restrict__ pos, int e) {
  int i = blockIdx.x * blockDim.x + threadIdx.x;
  if (i < e) {
    int d = dst[i];
    unsigned long long v = (1ull << 40) |
        (unsigned long long)(ew[i] * 16777216.0f + 0.5f);
    unsigned long long old = atomicAdd(&acc[d], v);
    pos[i] = (int)(old >> 40);
  }
}

__global__ void node_pass_k(const unsigned long long* __restrict__ acc,
                            float* __restrict__ dinv, int* __restrict__ cnt, int n) {
  int i = blockIdx.x * blockDim.x + threadIdx.x;
  if (i < n) {
    unsigned long long a = acc[i];
    double dfix = (double)(a & 0xFFFFFFFFFFull);
    float deg = (float)(dfix * (1.0 / 16777216.0) + 1.0);   // +1 self-loop
    dinv[i] = rsqrtf(deg);
    cnt[i] = (int)(a >> 40) + 1;                            // +1 self-loop
  }
}

__global__ __launch_bounds__(256) void block_reduce_k(const int* __restrict__ cnt,
                                                      int* bsum, int n) {
  __shared__ int s[256];
  int t = threadIdx.x;
  int i = blockIdx.x * 256 + t;
  s[t] = (i < n) ? cnt[i] : 0;
  __syncthreads();
  for (int off = 128; off; off >>= 1) {
    if (t < off) s[t] += s[t + off];
    __syncthreads();
  }
  if (t == 0) bsum[blockIdx.x] = s[0];
}

__global__ __launch_bounds__(256) void scan_bsums_k(int* bsum, int nb) {
  __shared__ int s[256];
  int t = threadIdx.x;
  s[t] = (t < nb) ? bsum[t] : 0;
  __syncthreads();
  for (int off = 1; off < 256; off <<= 1) {
    int v = (t >= off) ? s[t - off] : 0;
    __syncthreads();
    s[t] += v;
    __syncthreads();
  }
  if (t < nb) bsum[t] = (t == 0) ? 0 : s[t - 1];
}

__global__ __launch_bounds__(256) void scan_write_k(const int* __restrict__ cnt,
                                                    const int* __restrict__ bsum,
                                                    int* row_ptr, int n) {
  __shared__ int s[256];
  int t = threadIdx.x;
  int i = blockIdx.x * 256 + t;
  int c = (i < n) ? cnt[i] : 0;
  s[t] = c;
  __syncthreads();
  for (int off = 1; off < 256; off <<= 1) {
    int v = (t >= off) ? s[t - off] : 0;
    __syncthreads();
    s[t] += v;
    __syncthreads();
  }
  int ex = bsum[blockIdx.x] + ((t == 0) ? 0 : s[t - 1]);
  if (i < n) row_ptr[i] = ex;
  if (i == n - 1) row_ptr[n] = ex + c;
}

__global__ void scatter2_k(const int* __restrict__ src, const int* __restrict__ dst,
                           const float* __restrict__ ew, const int* __restrict__ pos,
                           const float* __restrict__ dinv, const int* __restrict__ rowp,
                           int2* __restrict__ csr, int e, int n) {
  int i = blockIdx.x * blockDim.x + threadIdx.x;
  if (i < e) {
    int s = src[i], d = dst[i];
    float w = dinv[s] * ew[i] * dinv[d];
    csr[rowp[d] + pos[i]] = make_int2(s, __float_as_int(w));
  } else if (i < e + n) {
    int v = i - e;
    float di = dinv[v];
    csr[rowp[v + 1] - 1] = make_int2(v, __float_as_int(di * di));  // self-loop last
  }
}

// ---- weight-chain precompute: P slices [48 cols x KTOT rows] f32 + rank-1 -
__global__ __launch_bounds__(256) void chains_k(
    const float* __restrict__ W_gcn, const float* __restrict__ b_gcn,
    const float* __restrict__ W_out, const float* __restrict__ b_out,
    float* __restrict__ Pf, float* __restrict__ rv) {
  __shared__ float T0[128 * 4];
  __shared__ float T1[128 * 4];
  const int b = blockIdx.y;          // 0..3
  const int j = b + 1;
  const int c0 = blockIdx.x * 4;     // col group base
  const int ks_all[4][4] = {{0, -1, -1, -1}, {1, 2, -1, -1}, {3, 4, 5, -1}, {6, 7, 8, 9}};
  const int t = threadIdx.x;
  const int lane = t & 63;
  const int wv = t >> 6;             // wave 0..3

  for (int idx = t; idx < 512; idx += 256) {
    int r = idx >> 2, c = idx & 3;
    T0[idx] = W_out[(size_t)(j * 128 + r) * 40 + c0 + c];
  }
  __syncthreads();
  float* Tc = T0;
  float* Tn = T1;
  for (int step = 0; step < j; ++step) {
    int kw = ks_all[b][j - 1 - step];
    {
      float s = b_gcn[kw * 128 + lane] * Tc[lane * 4 + wv] +
                b_gcn[kw * 128 + 64 + lane] * Tc[(64 + lane) * 4 + wv];
      for (int o = 32; o; o >>= 1) s += __shfl_down(s, o);
      if (lane == 0) atomicAdd(&rv[step * 40 + c0 + wv], s);
    }
    const float* W = W_gcn + (size_t)kw * 128 * 128;
    int r = t & 127;
    int ch = (t >> 7) << 1;          // 0 or 2
    float a0 = 0.f, a1 = 0.f;
    for (int k = 0; k < 128; k += 4) {
      float4 w4 = *(const float4*)&W[(size_t)r * 128 + k];
      a0 += w4.x * Tc[(k + 0) * 4 + ch] + w4.y * Tc[(k + 1) * 4 + ch] +
            w4.z * Tc[(k + 2) * 4 + ch] + w4.w * Tc[(k + 3) * 4 + ch];
      a1 += w4.x * Tc[(k + 0) * 4 + ch + 1] + w4.y * Tc[(k + 1) * 4 + ch + 1] +
            w4.z * Tc[(k + 2) * 4 + ch + 1] + w4.w * Tc[(k + 3) * 4 + ch + 1];
    }
    Tn[r * 4 + ch] = a0;
    Tn[r * 4 + ch + 1] = a1;
    __syncthreads();
    float* tmp = Tc; Tc = Tn; Tn = tmp;
  }
  for (int idx = t; idx < 512; idx += 256) {
    int r = idx >> 2, c = idx & 3;
    Pf[(size_t)(c0 + c) * KTOT + j * 128 + r] = Tc[idx];
  }
  if (b == 0) {
    for (int idx = t; idx < 512; idx += 256) {
      int r = idx >> 2, c = idx & 3;
      Pf[(size_t)(c0 + c) * KTOT + r] = W_out[(size_t)r * 40 + c0 + c];
    }
    if (blockIdx.x == 0 && t < 40) atomicAdd(&rv[t], b_out[t]);   // row_1 += b_out
  }
}

// ---- Wz collapse: Wzt[n][k] = bf16( sum_m W_in[k][m] * P(m,n) ), n=j*48+c --
// Also cz[n] = b_in . Pcol + rv[j][c]  (rank-1 bias terms fold into z_j).
__global__ __launch_bounds__(256) void wz_k(
    const float* __restrict__ W_in, const float* __restrict__ b_in,
    const float* __restrict__ Pf, const float* __restrict__ rv,
    unsigned short* __restrict__ Wzt, float* __restrict__ cz) {
  __shared__ float Pcol[128];
  __shared__ float bred[64];
  const int n = blockIdx.x;          // 0..239
  const int j = n / 48, c = n - j * 48;
  const int t = threadIdx.x;
  if (t < 128) Pcol[t] = Pf[(size_t)c * KTOT + j * 128 + t];
  __syncthreads();
  for (int k = t; k < F_IN; k += 256) {
    const float* wr = W_in + (size_t)k * 128;
    float s = 0.f;
    for (int m = 0; m < 128; m += 4) {
      float4 w4 = *(const float4*)&wr[m];
      s += w4.x * Pcol[m] + w4.y * Pcol[m + 1] +
           w4.z * Pcol[m + 2] + w4.w * Pcol[m + 3];
    }
    Wzt[(size_t)n * F_IN + k] = bf16_rne(s);
  }
  if (t < 64) bred[t] = b_in[t] * Pcol[t] + b_in[t + 64] * Pcol[t + 64];
  __syncthreads();
  if (t == 0) {
    float s = 0.f;
    for (int i = 0; i < 64; ++i) s += bred[i];
    float r = (j < 4 && c < 40) ? rv[j * 40 + c] : 0.f;
    cz[n] = s + r;
  }
}

// ------------- fused GEMM: Z[N,240] = bf16(x @ Wzt + cz) -------------------
// Round-4: 64x256 tile, BK=32, NT=16, but LDS cut 48->40 KB so ALL 782
// blocks are co-resident (4 blocks/CU x 40960 B = 160 KiB exactly).
// Round-3's 80 us was ~40 us work + ~40 us TAIL: 782 = 3x256+14 at 3
// blocks/CU meant a second phase running 14 blocks on 14 CUs (Occupancy
// 20.7% ~= (12 waves x t + 0.7 x t)/2t confirmed this).
// A is now REG-STAGED to bf16 (global f32 -> cvt -> swizzled ds_write):
//  - As shrinks 16->8 KB (bf16, double-buffered)
//  - fp32->bf16 cvt leaves the COMPUTE path; A-frag read = 1 ds_read_b128
//  - A swizzle applied at ds_write (reg-staged, rule-21 does not constrain)
// vmcnt discipline (per wave/stage: 2 A reg-loads then 4 B global_load_lds,
// in-order retirement): compiler auto-waits the A-reg use (it sees the dep);
// manual vmcnt(2) drains B(t) while A(t+1) stays in flight; lgkmcnt(0)
// before the barrier covers cross-wave ds_write visibility.
// waves_per_eu(4,4) pins RA at 128 VGPR (est ~110) -- a spill would be
// scratch VMEM and corrupt the vmcnt count, so lean registers matter.
__global__ __launch_bounds__(256)
__attribute__((amdgpu_waves_per_eu(4, 4)))
void gemm_xz_k(
    const float* __restrict__ A, const unsigned short* __restrict__ Wzt,
    const float* __restrict__ cz, unsigned short* __restrict__ Z, int M) {
  constexpr int K = F_IN, BK = 32, NT = K / BK;   // 16 k-stages
  __shared__ __align__(16) unsigned short As[2][64][32];  //  8 KB (bf16)
  __shared__ __align__(16) unsigned short Bs[2][256][32]; // 32 KB
  const int t = threadIdx.x;
  const int lane = t & 63;
  const int w = t >> 6;
  const int q = lane >> 4;
  const int l15 = lane & 15;
  const int wm = w >> 1, wn = w & 1;
  const int m0 = blockIdx.x * 64;

  // ---- A staging map: lane -> (row, 8-f32 chunk) ----
  const int ar = w * 16 + (lane >> 2);       // row 0..63
  const int ac = lane & 3;                   // 8-f32 chunk 0..3
  int gm = m0 + ar; if (gm >= M) gm = M - 1;
  const float* pA = A + (size_t)gm * K + (ac << 3);
  const int asw = (ac ^ (ar & 3)) << 3;      // swizzled bf16-slot offset in row

  // ---- B: per-lane pre-swizzled global source pointers (linear LDS dest) --
  // inst it in {0..3}: rows r = (w*4+it)*16 + (lane>>2), 16B chunk c = lane&3.
  // LDS chunk c of row r holds global chunk c ^ (r&3).
  const unsigned short* pB[4];
#pragma unroll
  for (int it = 0; it < 4; ++it) {
    int r = (w * 4 + it) * 16 + (lane >> 2);
    int c = lane & 3;
    pB[it] = Wzt + (size_t)r * K + ((c ^ (r & 3)) << 3);
  }

  f32x4 acc[2][8];
#pragma unroll
  for (int i = 0; i < 2; ++i)
#pragma unroll
    for (int j = 0; j < 8; ++j) acc[i][j] = (f32x4){0.f, 0.f, 0.f, 0.f};

  auto STAGE_B = [&](int buf, int ks) {
#pragma unroll
    for (int it = 0; it < 4; ++it)
      GLOAD_LDS16(pB[it] + ks * BK, &Bs[buf][(w * 4 + it) * 16][0] + lane * 8);
  };

  auto COMPUTE = [&](int buf) {
    bf16x8 af[2];
#pragma unroll
    for (int i = 0; i < 2; ++i) {
      int m = (wm << 5) + (i << 4) + l15;
      af[i] = *(const bf16x8*)&As[buf][m][(q ^ (m & 3)) << 3];
    }
#pragma unroll
    for (int j = 0; j < 8; ++j) {
      int nn = (wn << 7) + (j << 4) + l15;
      bf16x8 bfr = *(const bf16x8*)&Bs[buf][nn][(q ^ (nn & 3)) << 3];
#pragma unroll
      for (int i = 0; i < 2; ++i)
        acc[i][j] = __builtin_amdgcn_mfma_f32_16x16x32_bf16(af[i], bfr, acc[i][j], 0, 0, 0);
    }
  };

  // ---- prologue: A(0) regs + B(0) lds in flight (order: A older than B) ---
  float4 fa0 = *(const float4*)(pA + 0);
  float4 fa1 = *(const float4*)(pA + 4);
  STAGE_B(0, 0);

#pragma unroll
  for (int ts = 0; ts < NT; ++ts) {
    // cvt A(ts) (compiler inserts the vmcnt wait for fa0/fa1 here)
    uint4 ua;
    ua.x = (unsigned int)bf16_rne(fa0.x) | ((unsigned int)bf16_rne(fa0.y) << 16);
    ua.y = (unsigned int)bf16_rne(fa0.z) | ((unsigned int)bf16_rne(fa0.w) << 16);
    ua.z = (unsigned int)bf16_rne(fa1.x) | ((unsigned int)bf16_rne(fa1.y) << 16);
    ua.w = (unsigned int)bf16_rne(fa1.z) | ((unsigned int)bf16_rne(fa1.w) << 16);
    // issue A(ts+1) reg loads (younger than B(ts))
    if (ts + 1 < NT) {
      const float* p = pA + (ts + 1) * BK;
      fa0 = *(const float4*)(p + 0);
      fa1 = *(const float4*)(p + 4);
    }
    // swizzled ds_write of A(ts) bf16
    *(uint4*)&As[ts & 1][ar][asw] = ua;
    if (ts + 1 < NT) {
      asm volatile("s_waitcnt vmcnt(2)" ::: "memory");  // B(ts) landed in LDS
      STAGE_B((ts + 1) & 1, ts + 1);                    // 4 more in flight
    } else {
      asm volatile("s_waitcnt vmcnt(0)" ::: "memory");  // drain last B
    }
    asm volatile("s_waitcnt lgkmcnt(0)" ::: "memory");  // ds_writes retired
    __builtin_amdgcn_s_barrier();
    __builtin_amdgcn_sched_barrier(0);   // no ds_read hoists above the barrier
    COMPUTE(ts & 1);
    __builtin_amdgcn_sched_barrier(0);
    __builtin_amdgcn_s_barrier();        // compute done before buf reuse
  }

#pragma unroll
  for (int j = 0; j < 8; ++j) {
    int gcol = (wn << 7) + (j << 4) + l15;
    if (gcol >= ZW) continue;
    float bv = cz[gcol];
#pragma unroll
    for (int i = 0; i < 2; ++i) {
      int rb = m0 + (wm << 5) + (i << 4) + (q << 2);
#pragma unroll
      for (int r = 0; r < 4; ++r) {
        int row = rb + r;
        if (row < M) Z[(size_t)row * ZW + gcol] = bf16_rne(acc[i][j][r] + bv);
      }
    }
  }
}

// ---------------- Horner aggregation over 40-wide z blocks -----------------
// out = z0 + A(z1 + A(z2 + A(z3 + A z4)))   [z_k = Z block k, bf16]
// PASS 0: y1 = A*z4 + z3   PASS 1: y2 = A*y1 + z2
// PASS 2: y3 = A*y2 + z1   PASS 3: out = A*y3 + z0
// Horner state f32 [N][40]. 3 nodes per wave (lane groups of 20), 8-edge
// unroll; __any loops handle inter-group divergence.
template <int PASS>
__global__ __launch_bounds__(256) void agg2_k(
    const int* __restrict__ rowp, const int2* __restrict__ csr,
    const float* __restrict__ yin, const unsigned int* __restrict__ Zd,
    float* __restrict__ yout, int n) {
  const int lane = threadIdx.x & 63;
  const int wv = threadIdx.x >> 6;
  const int g = lane / 20;            // group 0..2 (g==3: idle)
  const int gl = lane - g * 20;       // 0..19 (dword-col within node)
  const int node = ((blockIdx.x << 2) + wv) * 3 + g;
  const bool alive = (g < 3) && (node < n);
  int beg = 0, end = 0;
  if (alive) { beg = rowp[node]; end = rowp[node + 1]; }
  float ax = 0.f, ay = 0.f;
  int j = beg;
  if (PASS == 0) {
    const unsigned int* in = Zd + 96 + gl;    // Z block4, dword stride 120
    while (__any(j + 8 <= end)) {
      if (j + 8 <= end) {
        int2 e0 = csr[j],     e1 = csr[j + 1], e2 = csr[j + 2], e3 = csr[j + 3];
        int2 e4 = csr[j + 4], e5 = csr[j + 5], e6 = csr[j + 6], e7 = csr[j + 7];
        unsigned int v0 = in[(size_t)e0.x * 120], v1 = in[(size_t)e1.x * 120];
        unsigned int v2 = in[(size_t)e2.x * 120], v3 = in[(size_t)e3.x * 120];
        unsigned int v4 = in[(size_t)e4.x * 120], v5 = in[(size_t)e5.x * 120];
        unsigned int v6 = in[(size_t)e6.x * 120], v7 = in[(size_t)e7.x * 120];
        float w0 = __int_as_float(e0.y), w1 = __int_as_float(e1.y);
        float w2 = __int_as_float(e2.y), w3 = __int_as_float(e3.y);
        float w4 = __int_as_float(e4.y), w5 = __int_as_float(e5.y);
        float w6 = __int_as_float(e6.y), w7 = __int_as_float(e7.y);
        ax += w0 * bf16_lo_f(v0) + w1 * bf16_lo_f(v1) +
              w2 * bf16_lo_f(v2) + w3 * bf16_lo_f(v3);
        ay += w0 * bf16_hi_f(v0) + w1 * bf16_hi_f(v1) +
              w2 * bf16_hi_f(v2) + w3 * bf16_hi_f(v3);
        ax += w4 * bf16_lo_f(v4) + w5 * bf16_lo_f(v5) +
              w6 * bf16_lo_f(v6) + w7 * bf16_lo_f(v7);
        ay += w4 * bf16_hi_f(v4) + w5 * bf16_hi_f(v5) +
              w6 * bf16_hi_f(v6) + w7 * bf16_hi_f(v7);
        j += 8;
      }
    }
    while (__any(j < end)) {
      if (j < end) {
        int2 e = csr[j];
        float w = __int_as_float(e.y);
        unsigned int v = in[(size_t)e.x * 120];
        ax += w * bf16_lo_f(v);
        ay += w * bf16_hi_f(v);
        ++j;
      }
    }
  } else {
    const float* in = yin + (gl << 1);        // f32 pair, row stride 40
    while (__any(j + 8 <= end)) {
      if (j + 8 <= end) {
        int2 e0 = csr[j],     e1 = csr[j + 1], e2 = csr[j + 2], e3 = csr[j + 3];
        int2 e4 = csr[j + 4], e5 = csr[j + 5], e6 = csr[j + 6], e7 = csr[j + 7];
        float2 v0 = *(const float2*)&in[(size_t)e0.x * 40];
        float2 v1 = *(const float2*)&in[(size_t)e1.x * 40];
        float2 v2 = *(const float2*)&in[(size_t)e2.x * 40];
        float2 v3 = *(const float2*)&in[(size_t)e3.x * 40];
        float2 v4 = *(const float2*)&in[(size_t)e4.x * 40];
        float2 v5 = *(const float2*)&in[(size_t)e5.x * 40];
        float2 v6 = *(const float2*)&in[(size_t)e6.x * 40];
        float2 v7 = *(const float2*)&in[(size_t)e7.x * 40];
        float w0 = __int_as_float(e0.y), w1 = __int_as_float(e1.y);
        float w2 = __int_as_float(e2.y), w3 = __int_as_float(e3.y);
        float w4 = __int_as_float(e4.y), w5 = __int_as_float(e5.y);
        float w6 = __int_as_float(e6.y), w7 = __int_as_float(e7.y);
        ax += w0 * v0.x + w1 * v1.x + w2 * v2.x + w3 * v3.x;
        ay += w0 * v0.y + w1 * v1.y + w2 * v2.y + w3 * v3.y;
        ax += w4 * v4.x + w5 * v5.x + w6 * v6.x + w7 * v7.x;
        ay += w4 * v4.y + w5 * v5.y + w6 * v6.y + w7 * v7.y;
        j += 8;
      }
    }
    while (__any(j < end)) {
      if (j < end) {
        int2 e = csr[j];
        float w = __int_as_float(e.y);
        float2 v = *(const float2*)&in[(size_t)e.x * 40];
        ax += w * v.x;
        ay += w * v.y;
        ++j;
      }
    }
  }
  if (alive) {
    unsigned int z = Zd[(size_t)node * 120 + (3 - PASS) * 24 + gl];
    float2 o;
    o.x = ax + bf16_lo_f(z);
    o.y = ay + bf16_hi_f(z);
    *(float2*)&yout[(size_t)node * 40 + (gl << 1)] = o;
  }
}

// ------------------------------- launcher ----------------------------------

extern "C" void kernel_launch(void* const* d_in, const int* in_sizes, int n_in,
                              void* d_out, int out_size, void* d_ws, size_t ws_size,
                              hipStream_t stream) {
  const float* x     = (const float*)d_in[0];
  const int*   eidx  = (const int*)  d_in[1];
  const float* ew    = (const float*)d_in[2];
  const float* W_in  = (const float*)d_in[3];
  const float* b_in  = (const float*)d_in[4];
  const float* W_gcn = (const float*)d_in[5];
  const float* b_gcn = (const float*)d_in[6];
  const float* W_out = (const float*)d_in[7];
  const float* b_out = (const float*)d_in[8];
  float* out = (float*)d_out;

  const int* src = eidx;
  const int* dst = eidx + N_EDGES;

  char* ws = (char*)d_ws;
  size_t off = 0;
  auto alloc = [&](size_t bytes) -> void* {
    void* p = ws + off;
    off += (bytes + 255) & ~(size_t)255;
    return p;
  };
  unsigned long long* acc = (unsigned long long*)alloc((size_t)N_NODES * 8);
  int*   pos    = (int*)  alloc((size_t)N_EDGES * 4);
  int*   cnt    = (int*)  alloc((size_t)N_NODES * 4);
  int*   rowp   = (int*)  alloc((size_t)(N_NODES + 1) * 4);
  float* dinv   = (float*)alloc((size_t)N_NODES * 4);
  int*   bsum   = (int*)  alloc((size_t)256 * 4);
  int2*  csr    = (int2*) alloc((size_t)TOT_E * 8);
  float* Pf     = (float*)alloc((size_t)48 * KTOT * 4);
  unsigned short* Wzt = (unsigned short*)alloc((size_t)NZP * F_IN * 2);
  float* cz     = (float*)alloc((size_t)NZP * 4);
  unsigned short* Z = (unsigned short*)alloc((size_t)N_NODES * ZW * 2);
  float* ya     = (float*)alloc((size_t)N_NODES * 40 * 4);
  float* yb     = (float*)alloc((size_t)N_NODES * 40 * 4);
  float* rv     = (float*)alloc((size_t)4 * 40 * 4);
  (void)ws_size; (void)in_sizes; (void)n_in; (void)out_size;

  dim3 b256(256);
  const int NB = (N_NODES + 255) / 256;
  const int GBZ = (N_NODES + 63) / 64;        // 782 blocks, all co-resident
  const int AB3 = (N_NODES + 11) / 12;        // 4167 blocks (12 nodes each)
  const unsigned int* Zd = (const unsigned int*)Z;

  hipMemsetAsync(acc, 0, (size_t)N_NODES * 8, stream);
  hipMemsetAsync(rv, 0, (size_t)4 * 40 * 4, stream);
  hipMemsetAsync(Pf, 0, (size_t)48 * KTOT * 4, stream);   // pad cols 40..47 = 0
  hipMemsetAsync(Wzt, 0, (size_t)NZP * F_IN * 2, stream); // pad rows 240..255 = 0
  hipMemsetAsync(cz, 0, (size_t)NZP * 4, stream);

  edge_pass1_k<<<(N_EDGES + 255) / 256, b256, 0, stream>>>(dst, ew, acc, pos, N_EDGES);
  node_pass_k<<<NB, b256, 0, stream>>>(acc, dinv, cnt, N_NODES);
  block_reduce_k<<<NB, b256, 0, stream>>>(cnt, bsum, N_NODES);
  scan_bsums_k<<<1, b256, 0, stream>>>(bsum, NB);
  scan_write_k<<<NB, b256, 0, stream>>>(cnt, bsum, rowp, N_NODES);
  scatter2_k<<<(TOT_E + 255) / 256, b256, 0, stream>>>(src, dst, ew, pos, dinv, rowp,
                                                       csr, N_EDGES, N_NODES);

  chains_k<<<dim3(10, 4), b256, 0, stream>>>(W_gcn, b_gcn, W_out, b_out, Pf, rv);
  wz_k<<<ZW, b256, 0, stream>>>(W_in, b_in, Pf, rv, Wzt, cz);

  // Z[N,240] = bf16(x @ Wzt + cz)
  gemm_xz_k<<<GBZ, b256, 0, stream>>>(x, Wzt, cz, Z, N_NODES);

  // Horner: out = z0 + A(z1 + A(z2 + A(z3 + A z4)))
  agg2_k<0><<<AB3, b256, 0, stream>>>(rowp, csr, nullptr, Zd, ya, N_NODES);
  agg2_k<1><<<AB3, b256, 0, stream>>>(rowp, csr, ya, Zd, yb, N_NODES);
  agg2_k<2><<<AB3, b256, 0, stream>>>(rowp, csr, yb, Zd, ya, N_NODES);
  agg2_k<3><<<AB3, b256, 0, stream>>>(rowp, csr, ya, Zd, out, N_NODES);
}

// Round 5
// 420.306 us; speedup vs baseline: 1.1502x; 1.0112x over previous
//
#include <hip/hip_runtime.h>
#include <cstdint>
#include <cstddef>

#define N_NODES 50000
#define N_EDGES 800000
#define F_IN    512
#define H_DIM   128
#define C_OUT   40
#define TOT_E   (N_EDGES + N_NODES)
#define KTOT    640             // P rows: h | u1 | u2 | u3 | u4
#define ZW      240             // Z row width: 5 blocks x 48
#define NZP     256             // Wzt rows padded to 256

typedef __attribute__((ext_vector_type(8))) __bf16 bf16x8;
typedef __attribute__((ext_vector_type(4))) float f32x4;

__device__ __forceinline__ unsigned short bf16_rne(float f) {
  unsigned int u = __float_as_uint(f);
  u += 0x7fffu + ((u >> 16) & 1u);
  return (unsigned short)(u >> 16);
}
__device__ __forceinline__ float bf16_lo_f(unsigned int u) { return __uint_as_float(u << 16); }
__device__ __forceinline__ float bf16_hi_f(unsigned int u) { return __uint_as_float(u & 0xffff0000u); }

// async global->LDS, 16B per lane; dest must be linear (base + lane*16)
#define GLOAD_LDS16(gp, lp)                                                        \
  __builtin_amdgcn_global_load_lds(                                                \
      (const __attribute__((address_space(1))) void*)(gp),                         \
      (__attribute__((address_space(3))) void*)(lp), 16, 0, 0)

// ----------------------------- setup kernels -------------------------------
// Single u64 atomic per edge: bits [40..63] = count, [0..39] = 2^-24 fixed-pt
// weighted degree. Returned old count = slot of edge in its dst bucket.

__global__ void edge_pass1_k(const int* __restrict__ dst, const float* __restrict__ ew,
                             unsigned long long* __restrict__ acc,
                             int* __restrict__ pos, int e) {
  int i = blockIdx.x * blockDim.x + threadIdx.x;
  if (i < e) {
    int d = dst[i];
    unsigned long long v = (1ull << 40) |
        (unsigned long long)(ew[i] * 16777216.0f + 0.5f);
    unsigned long long old = atomicAdd(&acc[d], v);
    pos[i] = (int)(old >> 40);
  }
}

__global__ void node_pass_k(const unsigned long long* __restrict__ acc,
                            float* __restrict__ dinv, int* __restrict__ cnt, int n) {
  int i = blockIdx.x * blockDim.x + threadIdx.x;
  if (i < n) {
    unsigned long long a = acc[i];
    double dfix = (double)(a & 0xFFFFFFFFFFull);
    float deg = (float)(dfix * (1.0 / 16777216.0) + 1.0);   // +1 self-loop
    dinv[i] = rsqrtf(deg);
    cnt[i] = (int)(a >> 40) + 1;                            // +1 self-loop
  }
}

__global__ __launch_bounds__(256) void block_reduce_k(const int* __restrict__ cnt,
                                                      int* bsum, int n) {
  __shared__ int s[256];
  int t = threadIdx.x;
  int i = blockIdx.x * 256 + t;
  s[t] = (i < n) ? cnt[i] : 0;
  __syncthreads();
  for (int off = 128; off; off >>= 1) {
    if (t < off) s[t] += s[t + off];
    __syncthreads();
  }
  if (t == 0) bsum[blockIdx.x] = s[0];
}

__global__ __launch_bounds__(256) void scan_bsums_k(int* bsum, int nb) {
  __shared__ int s[256];
  int t = threadIdx.x;
  s[t] = (t < nb) ? bsum[t] : 0;
  __syncthreads();
  for (int off = 1; off < 256; off <<= 1) {
    int v = (t >= off) ? s[t - off] : 0;
    __syncthreads();
    s[t] += v;
    __syncthreads();
  }
  if (t < nb) bsum[t] = (t == 0) ? 0 : s[t - 1];
}

__global__ __launch_bounds__(256) void scan_write_k(const int* __restrict__ cnt,
                                                    const int* __restrict__ bsum,
                                                    int* row_ptr, int n) {
  __shared__ int s[256];
  int t = threadIdx.x;
  int i = blockIdx.x * 256 + t;
  int c = (i < n) ? cnt[i] : 0;
  s[t] = c;
  __syncthreads();
  for (int off = 1; off < 256; off <<= 1) {
    int v = (t >= off) ? s[t - off] : 0;
    __syncthreads();
    s[t] += v;
    __syncthreads();
  }
  int ex = bsum[blockIdx.x] + ((t == 0) ? 0 : s[t - 1]);
  if (i < n) row_ptr[i] = ex;
  if (i == n - 1) row_ptr[n] = ex + c;
}

__global__ void scatter2_k(const int* __restrict__ src, const int* __restrict__ dst,
                           const float* __restrict__ ew, const int* __restrict__ pos,
                           const float* __restrict__ dinv, const int* __restrict__ rowp,
                           int2* __restrict__ csr, int e, int n) {
  int i = blockIdx.x * blockDim.x + threadIdx.x;
  if (i < e) {
    int s = src[i], d = dst[i];
    float w = dinv[s] * ew[i] * dinv[d];
    csr[rowp[d] + pos[i]] = make_int2(s, __float_as_int(w));
  } else if (i < e + n) {
    int v = i - e;
    float di = dinv[v];
    csr[rowp[v + 1] - 1] = make_int2(v, __float_as_int(di * di));  // self-loop last
  }
}

// ---- weight-chain precompute: P slices [48 cols x KTOT rows] f32 + rank-1 -
__global__ __launch_bounds__(256) void chains_k(
    const float* __restrict__ W_gcn, const float* __restrict__ b_gcn,
    const float* __restrict__ W_out, const float* __restrict__ b_out,
    float* __restrict__ Pf, float* __restrict__ rv) {
  __shared__ float T0[128 * 4];
  __shared__ float T1[128 * 4];
  const int b = blockIdx.y;          // 0..3
  const int j = b + 1;
  const int c0 = blockIdx.x * 4;     // col group base
  const int ks_all[4][4] = {{0, -1, -1, -1}, {1, 2, -1, -1}, {3, 4, 5, -1}, {6, 7, 8, 9}};
  const int t = threadIdx.x;
  const int lane = t & 63;
  const int wv = t >> 6;             // wave 0..3

  for (int idx = t; idx < 512; idx += 256) {
    int r = idx >> 2, c = idx & 3;
    T0[idx] = W_out[(size_t)(j * 128 + r) * 40 + c0 + c];
  }
  __syncthreads();
  float* Tc = T0;
  float* Tn = T1;
  for (int step = 0; step < j; ++step) {
    int kw = ks_all[b][j - 1 - step];
    {
      float s = b_gcn[kw * 128 + lane] * Tc[lane * 4 + wv] +
                b_gcn[kw * 128 + 64 + lane] * Tc[(64 + lane) * 4 + wv];
      for (int o = 32; o; o >>= 1) s += __shfl_down(s, o);
      if (lane == 0) atomicAdd(&rv[step * 40 + c0 + wv], s);
    }
    const float* W = W_gcn + (size_t)kw * 128 * 128;
    int r = t & 127;
    int ch = (t >> 7) << 1;          // 0 or 2
    float a0 = 0.f, a1 = 0.f;
    for (int k = 0; k < 128; k += 4) {
      float4 w4 = *(const float4*)&W[(size_t)r * 128 + k];
      a0 += w4.x * Tc[(k + 0) * 4 + ch] + w4.y * Tc[(k + 1) * 4 + ch] +
            w4.z * Tc[(k + 2) * 4 + ch] + w4.w * Tc[(k + 3) * 4 + ch];
      a1 += w4.x * Tc[(k + 0) * 4 + ch + 1] + w4.y * Tc[(k + 1) * 4 + ch + 1] +
            w4.z * Tc[(k + 2) * 4 + ch + 1] + w4.w * Tc[(k + 3) * 4 + ch + 1];
    }
    Tn[r * 4 + ch] = a0;
    Tn[r * 4 + ch + 1] = a1;
    __syncthreads();
    float* tmp = Tc; Tc = Tn; Tn = tmp;
  }
  for (int idx = t; idx < 512; idx += 256) {
    int r = idx >> 2, c = idx & 3;
    Pf[(size_t)(c0 + c) * KTOT + j * 128 + r] = Tc[idx];
  }
  if (b == 0) {
    for (int idx = t; idx < 512; idx += 256) {
      int r = idx >> 2, c = idx & 3;
      Pf[(size_t)(c0 + c) * KTOT + r] = W_out[(size_t)r * 40 + c0 + c];
    }
    if (blockIdx.x == 0 && t < 40) atomicAdd(&rv[t], b_out[t]);   // row_1 += b_out
  }
}

// ---- Wz collapse: Wzt[n][k] = bf16( sum_m W_in[k][m] * P(m,n) ), n=j*48+c --
// Also cz[n] = b_in . Pcol + rv[j][c]  (rank-1 bias terms fold into z_j).
__global__ __launch_bounds__(256) void wz_k(
    const float* __restrict__ W_in, const float* __restrict__ b_in,
    const float* __restrict__ Pf, const float* __restrict__ rv,
    unsigned short* __restrict__ Wzt, float* __restrict__ cz) {
  __shared__ float Pcol[128];
  __shared__ float bred[64];
  const int n = blockIdx.x;          // 0..239
  const int j = n / 48, c = n - j * 48;
  const int t = threadIdx.x;
  if (t < 128) Pcol[t] = Pf[(size_t)c * KTOT + j * 128 + t];
  __syncthreads();
  for (int k = t; k < F_IN; k += 256) {
    const float* wr = W_in + (size_t)k * 128;
    float s = 0.f;
    for (int m = 0; m < 128; m += 4) {
      float4 w4 = *(const float4*)&wr[m];
      s += w4.x * Pcol[m] + w4.y * Pcol[m + 1] +
           w4.z * Pcol[m + 2] + w4.w * Pcol[m + 3];
    }
    Wzt[(size_t)n * F_IN + k] = bf16_rne(s);
  }
  if (t < 64) bred[t] = b_in[t] * Pcol[t] + b_in[t + 64] * Pcol[t + 64];
  __syncthreads();
  if (t == 0) {
    float s = 0.f;
    for (int i = 0; i < 64; ++i) s += bred[i];
    float r = (j < 4 && c < 40) ? rv[j * 40 + c] : 0.f;
    cz[n] = s + r;
  }
}

// ------------- fused GEMM: Z[N,240] = bf16(x @ Wzt + cz) -------------------
// Round-5: same 64x256/BK=32 tile & 40KB LDS as round-4, but the load-issue
// order is fixed: STAGE_B(ts+1) is issued BEFORE the counted wait (round-1's
// proven T4 pattern). Rounds 3-4 waited for B(ts) and only then issued
// B(ts+1) -- consecutive stages' HBM latencies serialized, which is why both
// ran at ~half of round-1's pace regardless of tile shape.
// Count check at the wait: outstanding = B(ts)[4] + A(ts+1)[2] + B(ts+1)[4]
// = 10; vmcnt(6) drains exactly B(ts); A(ts+1)+B(ts+1) stay in flight
// across the barrier and COMPUTE.
__global__ __launch_bounds__(256)
__attribute__((amdgpu_waves_per_eu(4, 4)))
void gemm_xz_k(
    const float* __restrict__ A, const unsigned short* __restrict__ Wzt,
    const float* __restrict__ cz, unsigned short* __restrict__ Z, int M) {
  constexpr int K = F_IN, BK = 32, NT = K / BK;   // 16 k-stages
  __shared__ __align__(16) unsigned short As[2][64][32];  //  8 KB (bf16)
  __shared__ __align__(16) unsigned short Bs[2][256][32]; // 32 KB
  const int t = threadIdx.x;
  const int lane = t & 63;
  const int w = t >> 6;
  const int q = lane >> 4;
  const int l15 = lane & 15;
  const int wm = w >> 1, wn = w & 1;
  const int m0 = blockIdx.x * 64;

  // ---- A staging map: lane -> (row, 8-f32 chunk) ----
  const int ar = w * 16 + (lane >> 2);       // row 0..63
  const int ac = lane & 3;                   // 8-f32 chunk 0..3
  int gm = m0 + ar; if (gm >= M) gm = M - 1;
  const float* pA = A + (size_t)gm * K + (ac << 3);
  const int asw = (ac ^ (ar & 3)) << 3;      // swizzled bf16-slot offset in row

  // ---- B: per-lane pre-swizzled global source pointers (linear LDS dest) --
  const unsigned short* pB[4];
#pragma unroll
  for (int it = 0; it < 4; ++it) {
    int r = (w * 4 + it) * 16 + (lane >> 2);
    int c = lane & 3;
    pB[it] = Wzt + (size_t)r * K + ((c ^ (r & 3)) << 3);
  }

  f32x4 acc[2][8];
#pragma unroll
  for (int i = 0; i < 2; ++i)
#pragma unroll
    for (int j = 0; j < 8; ++j) acc[i][j] = (f32x4){0.f, 0.f, 0.f, 0.f};

  auto STAGE_B = [&](int buf, int ks) {
#pragma unroll
    for (int it = 0; it < 4; ++it)
      GLOAD_LDS16(pB[it] + ks * BK, &Bs[buf][(w * 4 + it) * 16][0] + lane * 8);
  };

  auto COMPUTE = [&](int buf) {
    bf16x8 af[2];
#pragma unroll
    for (int i = 0; i < 2; ++i) {
      int m = (wm << 5) + (i << 4) + l15;
      af[i] = *(const bf16x8*)&As[buf][m][(q ^ (m & 3)) << 3];
    }
#pragma unroll
    for (int j = 0; j < 8; ++j) {
      int nn = (wn << 7) + (j << 4) + l15;
      bf16x8 bfr = *(const bf16x8*)&Bs[buf][nn][(q ^ (nn & 3)) << 3];
#pragma unroll
      for (int i = 0; i < 2; ++i)
        acc[i][j] = __builtin_amdgcn_mfma_f32_16x16x32_bf16(af[i], bfr, acc[i][j], 0, 0, 0);
    }
  };

  // ---- prologue: A(0) regs + B(0) lds in flight (order: A older than B) ---
  float4 fa0 = *(const float4*)(pA + 0);
  float4 fa1 = *(const float4*)(pA + 4);
  STAGE_B(0, 0);

#pragma unroll
  for (int ts = 0; ts < NT; ++ts) {
    // cvt A(ts) (compiler inserts the vmcnt wait for fa0/fa1 here; B(ts)
    // stays outstanding because it is younger than the A regs)
    uint4 ua;
    ua.x = (unsigned int)bf16_rne(fa0.x) | ((unsigned int)bf16_rne(fa0.y) << 16);
    ua.y = (unsigned int)bf16_rne(fa0.z) | ((unsigned int)bf16_rne(fa0.w) << 16);
    ua.z = (unsigned int)bf16_rne(fa1.x) | ((unsigned int)bf16_rne(fa1.y) << 16);
    ua.w = (unsigned int)bf16_rne(fa1.z) | ((unsigned int)bf16_rne(fa1.w) << 16);
    // issue A(ts+1) reg loads (younger than B(ts), older than B(ts+1))
    if (ts + 1 < NT) {
      const float* p = pA + (ts + 1) * BK;
      fa0 = *(const float4*)(p + 0);
      fa1 = *(const float4*)(p + 4);
    }
    // swizzled ds_write of A(ts) bf16
    *(uint4*)&As[ts & 1][ar][asw] = ua;
    if (ts + 1 < NT) {
      STAGE_B((ts + 1) & 1, ts + 1);                    // issue BEFORE wait
      asm volatile("s_waitcnt vmcnt(6)" ::: "memory");  // B(ts) landed; 6 fly
    } else {
      asm volatile("s_waitcnt vmcnt(0)" ::: "memory");  // drain last B
    }
    asm volatile("s_waitcnt lgkmcnt(0)" ::: "memory");  // ds_writes retired
    __builtin_amdgcn_s_barrier();
    __builtin_amdgcn_sched_barrier(0);   // no ds_read hoists above the barrier
    COMPUTE(ts & 1);
    __builtin_amdgcn_sched_barrier(0);
    __builtin_amdgcn_s_barrier();        // compute done before buf reuse
  }

#pragma unroll
  for (int j = 0; j < 8; ++j) {
    int gcol = (wn << 7) + (j << 4) + l15;
    if (gcol >= ZW) continue;
    float bv = cz[gcol];
#pragma unroll
    for (int i = 0; i < 2; ++i) {
      int rb = m0 + (wm << 5) + (i << 4) + (q << 2);
#pragma unroll
      for (int r = 0; r < 4; ++r) {
        int row = rb + r;
        if (row < M) Z[(size_t)row * ZW + gcol] = bf16_rne(acc[i][j][r] + bv);
      }
    }
  }
}

// ---------------- Horner aggregation over 40-wide z blocks -----------------
// out = z0 + A(z1 + A(z2 + A(z3 + A z4)))   [z_k = Z block k, bf16]
// PASS 0: y1 = A*z4 + z3   PASS 1: y2 = A*y1 + z2
// PASS 2: y3 = A*y2 + z1   PASS 3: out = A*y3 + z0
// Horner state f32 [N][40]. 3 nodes per wave (lane groups of 20).
// Round-5: the remainder loop (1 edge per __any round, ~3-6 serialized
// full-latency rounds per wave) is gone -- ONE uniform predicated 8-batch
// loop. OOB edges clamp to end-1 with weight 0: x + 0.0f is bit-exact
// identity, so the FP sum is IDENTICAL to the unpredicated version.
template <int PASS>
__global__ __launch_bounds__(256) void agg2_k(
    const int* __restrict__ rowp, const int2* __restrict__ csr,
    const float* __restrict__ yin, const unsigned int* __restrict__ Zd,
    float* __restrict__ yout, int n) {
  const int lane = threadIdx.x & 63;
  const int wv = threadIdx.x >> 6;
  const int g = lane / 20;            // group 0..2 (g==3: idle)
  const int gl = lane - g * 20;       // 0..19 (dword-col within node)
  const int node = ((blockIdx.x << 2) + wv) * 3 + g;
  const bool alive = (g < 3) && (node < n);
  int beg = 0, end = 0;
  if (alive) { beg = rowp[node]; end = rowp[node + 1]; }
  float ax = 0.f, ay = 0.f;
  int j = beg;
  const int eL = end - 1;             // last valid edge (deg >= 1 always)
  if (PASS == 0) {
    const unsigned int* in = Zd + 96 + gl;    // Z block4, dword stride 120
    while (__any(j < end)) {
      if (j < end) {
        int i0 = j,     i1 = min(j + 1, eL), i2 = min(j + 2, eL), i3 = min(j + 3, eL);
        int i4 = min(j + 4, eL), i5 = min(j + 5, eL), i6 = min(j + 6, eL), i7 = min(j + 7, eL);
        int2 e0 = csr[i0], e1 = csr[i1], e2 = csr[i2], e3 = csr[i3];
        int2 e4 = csr[i4], e5 = csr[i5], e6 = csr[i6], e7 = csr[i7];
        unsigned int v0 = in[(size_t)e0.x * 120], v1 = in[(size_t)e1.x * 120];
        unsigned int v2 = in[(size_t)e2.x * 120], v3 = in[(size_t)e3.x * 120];
        unsigned int v4 = in[(size_t)e4.x * 120], v5 = in[(size_t)e5.x * 120];
        unsigned int v6 = in[(size_t)e6.x * 120], v7 = in[(size_t)e7.x * 120];
        float w0 = __int_as_float(e0.y);
        float w1 = (j + 1 < end) ? __int_as_float(e1.y) : 0.f;
        float w2 = (j + 2 < end) ? __int_as_float(e2.y) : 0.f;
        float w3 = (j + 3 < end) ? __int_as_float(e3.y) : 0.f;
        float w4 = (j + 4 < end) ? __int_as_float(e4.y) : 0.f;
        float w5 = (j + 5 < end) ? __int_as_float(e5.y) : 0.f;
        float w6 = (j + 6 < end) ? __int_as_float(e6.y) : 0.f;
        float w7 = (j + 7 < end) ? __int_as_float(e7.y) : 0.f;
        ax += w0 * bf16_lo_f(v0) + w1 * bf16_lo_f(v1) +
              w2 * bf16_lo_f(v2) + w3 * bf16_lo_f(v3);
        ay += w0 * bf16_hi_f(v0) + w1 * bf16_hi_f(v1) +
              w2 * bf16_hi_f(v2) + w3 * bf16_hi_f(v3);
        ax += w4 * bf16_lo_f(v4) + w5 * bf16_lo_f(v5) +
              w6 * bf16_lo_f(v6) + w7 * bf16_lo_f(v7);
        ay += w4 * bf16_hi_f(v4) + w5 * bf16_hi_f(v5) +
              w6 * bf16_hi_f(v6) + w7 * bf16_hi_f(v7);
      }
      j += 8;
    }
  } else {
    const float* in = yin + (gl << 1);        // f32 pair, row stride 40
    while (__any(j < end)) {
      if (j < end) {
        int i0 = j,     i1 = min(j + 1, eL), i2 = min(j + 2, eL), i3 = min(j + 3, eL);
        int i4 = min(j + 4, eL), i5 = min(j + 5, eL), i6 = min(j + 6, eL), i7 = min(j + 7, eL);
        int2 e0 = csr[i0], e1 = csr[i1], e2 = csr[i2], e3 = csr[i3];
        int2 e4 = csr[i4], e5 = csr[i5], e6 = csr[i6], e7 = csr[i7];
        float2 v0 = *(const float2*)&in[(size_t)e0.x * 40];
        float2 v1 = *(const float2*)&in[(size_t)e1.x * 40];
        float2 v2 = *(const float2*)&in[(size_t)e2.x * 40];
        float2 v3 = *(const float2*)&in[(size_t)e3.x * 40];
        float2 v4 = *(const float2*)&in[(size_t)e4.x * 40];
        float2 v5 = *(const float2*)&in[(size_t)e5.x * 40];
        float2 v6 = *(const float2*)&in[(size_t)e6.x * 40];
        float2 v7 = *(const float2*)&in[(size_t)e7.x * 40];
        float w0 = __int_as_float(e0.y);
        float w1 = (j + 1 < end) ? __int_as_float(e1.y) : 0.f;
        float w2 = (j + 2 < end) ? __int_as_float(e2.y) : 0.f;
        float w3 = (j + 3 < end) ? __int_as_float(e3.y) : 0.f;
        float w4 = (j + 4 < end) ? __int_as_float(e4.y) : 0.f;
        float w5 = (j + 5 < end) ? __int_as_float(e5.y) : 0.f;
        float w6 = (j + 6 < end) ? __int_as_float(e6.y) : 0.f;
        float w7 = (j + 7 < end) ? __int_as_float(e7.y) : 0.f;
        ax += w0 * v0.x + w1 * v1.x + w2 * v2.x + w3 * v3.x;
        ay += w0 * v0.y + w1 * v1.y + w2 * v2.y + w3 * v3.y;
        ax += w4 * v4.x + w5 * v5.x + w6 * v6.x + w7 * v7.x;
        ay += w4 * v4.y + w5 * v5.y + w6 * v6.y + w7 * v7.y;
      }
      j += 8;
    }
  }
  if (alive) {
    unsigned int z = Zd[(size_t)node * 120 + (3 - PASS) * 24 + gl];
    float2 o;
    o.x = ax + bf16_lo_f(z);
    o.y = ay + bf16_hi_f(z);
    *(float2*)&yout[(size_t)node * 40 + (gl << 1)] = o;
  }
}

// ------------------------------- launcher ----------------------------------

extern "C" void kernel_launch(void* const* d_in, const int* in_sizes, int n_in,
                              void* d_out, int out_size, void* d_ws, size_t ws_size,
                              hipStream_t stream) {
  const float* x     = (const float*)d_in[0];
  const int*   eidx  = (const int*)  d_in[1];
  const float* ew    = (const float*)d_in[2];
  const float* W_in  = (const float*)d_in[3];
  const float* b_in  = (const float*)d_in[4];
  const float* W_gcn = (const float*)d_in[5];
  const float* b_gcn = (const float*)d_in[6];
  const float* W_out = (const float*)d_in[7];
  const float* b_out = (const float*)d_in[8];
  float* out = (float*)d_out;

  const int* src = eidx;
  const int* dst = eidx + N_EDGES;

  char* ws = (char*)d_ws;
  size_t off = 0;
  auto alloc = [&](size_t bytes) -> void* {
    void* p = ws + off;
    off += (bytes + 255) & ~(size_t)255;
    return p;
  };
  unsigned long long* acc = (unsigned long long*)alloc((size_t)N_NODES * 8);
  int*   pos    = (int*)  alloc((size_t)N_EDGES * 4);
  int*   cnt    = (int*)  alloc((size_t)N_NODES * 4);
  int*   rowp   = (int*)  alloc((size_t)(N_NODES + 1) * 4);
  float* dinv   = (float*)alloc((size_t)N_NODES * 4);
  int*   bsum   = (int*)  alloc((size_t)256 * 4);
  int2*  csr    = (int2*) alloc((size_t)TOT_E * 8);
  float* Pf     = (float*)alloc((size_t)48 * KTOT * 4);
  unsigned short* Wzt = (unsigned short*)alloc((size_t)NZP * F_IN * 2);
  float* cz     = (float*)alloc((size_t)NZP * 4);
  unsigned short* Z = (unsigned short*)alloc((size_t)N_NODES * ZW * 2);
  float* ya     = (float*)alloc((size_t)N_NODES * 40 * 4);
  float* yb     = (float*)alloc((size_t)N_NODES * 40 * 4);
  float* rv     = (float*)alloc((size_t)4 * 40 * 4);
  (void)ws_size; (void)in_sizes; (void)n_in; (void)out_size;

  dim3 b256(256);
  const int NB = (N_NODES + 255) / 256;
  const int GBZ = (N_NODES + 63) / 64;        // 782 blocks
  const int AB3 = (N_NODES + 11) / 12;        // 4167 blocks (12 nodes each)
  const unsigned int* Zd = (const unsigned int*)Z;

  hipMemsetAsync(acc, 0, (size_t)N_NODES * 8, stream);
  hipMemsetAsync(rv, 0, (size_t)4 * 40 * 4, stream);
  hipMemsetAsync(Pf, 0, (size_t)48 * KTOT * 4, stream);   // pad cols 40..47 = 0
  hipMemsetAsync(Wzt, 0, (size_t)NZP * F_IN * 2, stream); // pad rows 240..255 = 0
  hipMemsetAsync(cz, 0, (size_t)NZP * 4, stream);

  edge_pass1_k<<<(N_EDGES + 255) / 256, b256, 0, stream>>>(dst, ew, acc, pos, N_EDGES);
  node_pass_k<<<NB, b256, 0, stream>>>(acc, dinv, cnt, N_NODES);
  block_reduce_k<<<NB, b256, 0, stream>>>(cnt, bsum, N_NODES);
  scan_bsums_k<<<1, b256, 0, stream>>>(bsum, NB);
  scan_write_k<<<NB, b256, 0, stream>>>(cnt, bsum, rowp, N_NODES);
  scatter2_k<<<(TOT_E + 255) / 256, b256, 0, stream>>>(src, dst, ew, pos, dinv, rowp,
                                                       csr, N_EDGES, N_NODES);

  chains_k<<<dim3(10, 4), b256, 0, stream>>>(W_gcn, b_gcn, W_out, b_out, Pf, rv);
  wz_k<<<ZW, b256, 0, stream>>>(W_in, b_in, Pf, rv, Wzt, cz);

  // Z[N,240] = bf16(x @ Wzt + cz)
  gemm_xz_k<<<GBZ, b256, 0, stream>>>(x, Wzt, cz, Z, N_NODES);

  // Horner: out = z0 + A(z1 + A(z2 + A(z3 + A z4)))
  agg2_k<0><<<AB3, b256, 0, stream>>>(rowp, csr, nullptr, Zd, ya, N_NODES);
  agg2_k<1><<<AB3, b256, 0, stream>>>(rowp, csr, ya, Zd, yb, N_NODES);
  agg2_k<2><<<AB3, b256, 0, stream>>>(rowp, csr, yb, Zd, ya, N_NODES);
  agg2_k<3><<<AB3, b256, 0, stream>>>(rowp, csr, ya, Zd, out, N_NODES);
}